// Round 16
// baseline (434.892 us; speedup 1.0000x reference)
//
#include <hip/hip_runtime.h>
#include <cmath>

#define B_   128
#define N_   39
#define KNN_ 10
#define H_   256
#define K1_  32
#define K2_  26
#define K3_  21

static inline int cdiv(int a, int b) { return (a + b - 1) / b; }

typedef __attribute__((ext_vector_type(8))) short short8;
typedef __attribute__((ext_vector_type(4))) short short4v;
typedef __attribute__((ext_vector_type(4))) float floatx4;

__device__ inline short f2b(float f) {   // fp32 -> bf16 RNE
  unsigned u = __float_as_uint(f);
  u += 0x7fff + ((u >> 16) & 1);
  return (short)(u >> 16);
}
__device__ inline float b2f(short h) {
  return __uint_as_float(((unsigned)(unsigned short)h) << 16);
}
__device__ inline void f2b3(float v, short& h, short& m, short& l) {  // v ~= h+m+l (24 bits)
  h = f2b(v);
  float r1 = v - b2f(h);
  m = f2b(r1);
  l = f2b(r1 - b2f(m));
}

// async global->LDS 16B (dest is wave-uniform base + lane*16: pass lane-linear ptr)
__device__ __forceinline__ void gl_lds16(const short* g, short* l) {
  __builtin_amdgcn_global_load_lds(
      (const __attribute__((address_space(1))) unsigned int*)g,
      (__attribute__((address_space(3))) unsigned int*)l, 16, 0, 0);
}

// ------------- one-shot prep (flattened 1-D grid, exact per-task block ranges) -------------
// task 8: zero xoutb scatter targets; task 9: zero bn column-sum accumulators.
__global__ void prep_kernel(
    const float* __restrict__ w1, const float* __restrict__ w2,
    const float* __restrict__ w3, const float* __restrict__ w6,
    const float* __restrict__ l4, const float* __restrict__ l5,
    const float* __restrict__ x, const float* __restrict__ adj,
    short* __restrict__ wt1h, short* __restrict__ wt1m, short* __restrict__ wt1l,
    short* __restrict__ wt2h, short* __restrict__ wt2m, short* __restrict__ wt2l,
    short* __restrict__ wt3h, short* __restrict__ wt3m, short* __restrict__ wt3l,
    short* __restrict__ wt6h, short* __restrict__ wt6m,
    short* __restrict__ l4h, short* __restrict__ l4m,
    short* __restrict__ l5h, short* __restrict__ l5m,
    short* __restrict__ xsph, short* __restrict__ xspm, short* __restrict__ xspl,
    float* __restrict__ deg, short* __restrict__ zbase, double* __restrict__ bnsum) {
  int blk = blockIdx.x;
  int task, base;
  if      (blk < 128)  { task = 0; base = 0; }
  else if (blk < 640)  { task = 1; base = 128; }
  else if (blk < 1152) { task = 2; base = 640; }
  else if (blk < 1230) { task = 3; base = 1152; }
  else if (blk < 1486) { task = 4; base = 1230; }
  else if (blk < 1614) { task = 5; base = 1486; }
  else if (blk < 2862) { task = 6; base = 1614; }
  else if (blk < 2882) { task = 7; base = 2862; }
  else if (blk < 6626) { task = 8; base = 2882; }
  else                 { task = 9; base = 6626; }
  int t = (blk - base) * 256 + threadIdx.x;
  if (task == 0) {            // wcat1 tripleT: [512][64], K=39 padded
    if (t >= 512 * 64) return;
    int nn = t >> 6, k = t & 63;
    float v = 0.f;
    if (k < 39) v = (nn < 256) ? w1[k * 256 + nn] - w1[(39 + k) * 256 + nn]
                               : w1[(39 + k) * 256 + (nn - 256)];
    short h, m, l; f2b3(v, h, m, l);
    wt1h[t] = h; wt1m[t] = m; wt1l[t] = l;
  } else if (task == 1) {     // wcat2 tripleT: [512][256]
    if (t >= 512 * 256) return;
    int nn = t >> 8, k = t & 255;
    float v = (nn < 256) ? w2[k * 256 + nn] - w2[(256 + k) * 256 + nn]
                         : w2[(256 + k) * 256 + (nn - 256)];
    short h, m, l; f2b3(v, h, m, l);
    wt2h[t] = h; wt2m[t] = m; wt2l[t] = l;
  } else if (task == 2) {     // wcat3 tripleT
    if (t >= 512 * 256) return;
    int nn = t >> 8, k = t & 255;
    float v = (nn < 256) ? w3[k * 256 + nn] - w3[(256 + k) * 256 + nn]
                         : w3[(256 + k) * 256 + (nn - 256)];
    short h, m, l; f2b3(v, h, m, l);
    wt3h[t] = h; wt3m[t] = m; wt3l[t] = l;
  } else if (task == 3) {     // wcat6 T (h,m): [78][256]
    if (t >= 78 * 256) return;
    int nn = t >> 8, k = t & 255;
    float v = (nn < 39) ? w6[k * 39 + nn] - w6[(256 + k) * 39 + nn]
                        : w6[(256 + k) * 39 + (nn - 39)];
    short h, m, l; f2b3(v, h, m, l);
    wt6h[t] = h; wt6m[t] = m;
  } else if (task == 4) {     // lin4 T (h,m): [256][256]
    if (t >= 256 * 256) return;
    int nn = t >> 8, k = t & 255;
    short h, m, l; f2b3(l4[k * 256 + nn], h, m, l);
    l4h[t] = h; l4m[t] = m;
  } else if (task == 5) {     // lin5 T (h,m): [128][256]
    if (t >= 128 * 256) return;
    int nn = t >> 8, k = t & 255;
    short h, m, l; f2b3(l5[k * 128 + nn], h, m, l);
    l5h[t] = h; l5m[t] = m;
  } else if (task == 6) {     // x split: [4992][64], F=39 padded
    if (t >= 4992 * 64) return;
    int r = t >> 6, k = t & 63;
    float v = (k < 39) ? x[r * 39 + k] : 0.f;
    short h, m, l; f2b3(v, h, m, l);
    xsph[t] = h; xspm[t] = m; xspl[t] = l;
  } else if (task == 7) {     // degree
    if (t >= B_ * N_) return;
    const float* row = adj + (size_t)t * N_;
    float s = 0.f;
    for (int j = 0; j < N_; ++j) s += row[j];
    deg[t] = s;
  } else if (task == 8) {     // zero xoutb (958464 x 16B chunks)
    if (t >= 958464) return;
    short8 zz = {};
    *(short8*)&zbase[(size_t)t * 8] = zz;
  } else {                    // zero bn sums: 3 levels x 512 doubles
    if (t >= 256) return;
    for (int j = 0; j < 6; ++j) bnsum[t + j * 256] = 0.0;
  }
}

// ======== fused KNN + GEMM (one dispatch; block role by blockIdx.x) ========
// knn: blocks [0, knnB): MFMA gram + rank-parallel KNN (per graph); register staging.
// gemm: blocks [knnB, ...): C = A·W^T via global_load_lds width-16 staging into unpadded
// [128][32] tiles with XOR chunk swizzle c' = c ^ ((row>>1)&3).
// gemm work index is XCD-chunk-swizzled (m204 bijection, knnB%8==0).
// M%128==0 required; store guard on N. Both paths 512 thr. nterms via gnt (2/3-term split).
__global__ __launch_bounds__(512) void knn_gemm_kernel(
    const short* __restrict__ kxh, const short* __restrict__ kxm, const short* __restrict__ kxl,
    int knt, int kKs, int kn, int kF32, int* __restrict__ idx, int knnB,
    const short* __restrict__ Ah, const short* __restrict__ Am, const short* __restrict__ Al,
    int gnt, int gK,
    const short* __restrict__ Wh, const short* __restrict__ Wm, const short* __restrict__ Wl,
    float* __restrict__ C0, int gM, int gN, int gyB,
    size_t Astride, size_t Cstride) {
  extern __shared__ char smem[];
  int tid = threadIdx.x;
  int wave = tid >> 6, lane = tid & 63;
  int lm = lane & 15, lk = (lane >> 4) * 8;
  if ((int)blockIdx.x < knnB) {
    // ---------------- KNN path (register staging) ----------------
    short* sh_h = (short*)smem;
    short* sh_m = sh_h + 48 * 40;
    short* sh_l = sh_m + 48 * 40;
    float* Gs   = (float*)(sh_l + 48 * 40);    // [48][49]
    float* diag = Gs + 48 * 49;
    int b = blockIdx.x;
    int nt = (kn + 15) >> 4;
    int tasks = nt * nt;
    floatx4 acc[2] = {};
    int stage_elems = 384 * knt;
    for (int k0 = 0; k0 < kF32; k0 += 32) {
      for (int e = tid; e < stage_elems; e += 512) {
        int a = e / 384, rem = e - a * 384;
        int r = rem >> 3, c4 = (rem & 7) * 4;
        const short* src = (a == 0) ? kxh : (a == 1) ? kxm : kxl;
        short* dst = (a == 0) ? sh_h : (a == 1) ? sh_m : sh_l;
        *(short4v*)&dst[r * 40 + c4] =
            *(const short4v*)&src[((size_t)(b * kn + r)) * kKs + k0 + c4];
      }
      __syncthreads();
#pragma unroll
      for (int ai = 0; ai < 2; ++ai) {
        int t = wave + ai * 8;
        if (t < tasks) {
          int ti = t / nt, tj = t - ti * nt;
          int ra = (ti * 16 + lm) * 40 + lk;
          int rb = (tj * 16 + lm) * 40 + lk;
          short8 ah = *(const short8*)&sh_h[ra];
          short8 am = *(const short8*)&sh_m[ra];
          short8 bh = *(const short8*)&sh_h[rb];
          short8 bm = *(const short8*)&sh_m[rb];
          floatx4 a = acc[ai];
          a = __builtin_amdgcn_mfma_f32_16x16x32_bf16(ah, bh, a, 0, 0, 0);
          a = __builtin_amdgcn_mfma_f32_16x16x32_bf16(ah, bm, a, 0, 0, 0);
          a = __builtin_amdgcn_mfma_f32_16x16x32_bf16(am, bh, a, 0, 0, 0);
          if (knt == 3) {
            short8 al = *(const short8*)&sh_l[ra];
            short8 bl = *(const short8*)&sh_l[rb];
            a = __builtin_amdgcn_mfma_f32_16x16x32_bf16(ah, bl, a, 0, 0, 0);
            a = __builtin_amdgcn_mfma_f32_16x16x32_bf16(al, bh, a, 0, 0, 0);
            a = __builtin_amdgcn_mfma_f32_16x16x32_bf16(am, bm, a, 0, 0, 0);
          }
          acc[ai] = a;
        }
      }
      __syncthreads();
    }
#pragma unroll
    for (int ai = 0; ai < 2; ++ai) {
      int t = wave + ai * 8;
      if (t < tasks) {
        int ti = t / nt, tj = t - ti * nt;
        int col = tj * 16 + lm;
        int rbase = ti * 16 + (lane >> 4) * 4;
#pragma unroll
        for (int r = 0; r < 4; ++r) Gs[(rbase + r) * 49 + col] = acc[ai][r];
      }
    }
    __syncthreads();
    if (tid < 48) diag[tid] = (tid < kn) ? Gs[tid * 49 + tid] : INFINITY;
    __syncthreads();
    for (int row = wave; row < kn; row += 8) {
      float gii = diag[row];
      float dj = (lane < kn) ? (gii + diag[lane] - 2.f * Gs[row * 49 + lane]) : INFINITY;
      int rank = 0;
      for (int j = 0; j < kn; ++j) {
        float djp = gii + diag[j] - 2.f * Gs[row * 49 + j];
        rank += (djp < dj || (djp == dj && j < lane)) ? 1 : 0;
      }
      if (lane < kn && rank < KNN_)
        idx[(size_t)(b * kn + row) * KNN_ + rank] = lane;
    }
  } else {
    // ---------------- GEMM path: global_load_lds staging + XOR chunk swizzle ----------------
    short* AshL = (short*)smem;                 // [128][32] per term (8192 B each)
    short* AsmL = AshL + 4096;
    short* AslL = AsmL + 4096;
    short* BshL = (short*)smem + gnt * 4096;
    short* BsmL = BshL + 4096;
    short* BslL = BsmL + 4096;
    int gb = blockIdx.x - knnB;
    int gxB = (gN + 127) >> 7;
    // m204 bijective XCD chunk swizzle: xcd = gb&7 (knnB%8==0), j-th block on that xcd
    int nb = (int)gridDim.x - knnB;
    int xcd = gb & 7, j = gb >> 3;
    int q8 = nb >> 3, r8 = nb & 7;
    int work = (xcd < r8 ? xcd * (q8 + 1) : r8 * (q8 + 1) + (xcd - r8) * q8) + j;
    int gx = work % gxB;
    int rest = work / gxB;
    int gy = rest % gyB;
    int gz = rest / gyB;
    const short* A_h = Ah + (size_t)gz * Astride;
    const short* A_m = Am ? Am + (size_t)gz * Astride : nullptr;
    const short* A_l = Al ? Al + (size_t)gz * Astride : nullptr;
    float* C = C0 + (size_t)gz * Cstride;
    int row0 = gy * 128, col0 = gx * 128;
    int wm = wave & 1, wn = wave >> 1;
    // staging coords: thread tid -> LDS chunk (row=tid>>2, c=tid&3); source chunk c^((row>>1)&3)
    int srow = tid >> 2;
    int scs = ((tid & 3) ^ ((srow >> 1) & 3)) << 3;   // swizzled source offset (shorts)
    size_t gArow = (size_t)(row0 + srow) * gK;
    size_t gBrow = (size_t)(col0 + srow) * gK;
    short* ldsA = AshL + tid * 8;   // lane-linear dests (16 B per lane)
    short* ldsAm = AsmL + tid * 8;
    short* ldsAl = AslL + tid * 8;
    short* ldsB = BshL + tid * 8;
    short* ldsBm = BsmL + tid * 8;
    short* ldsBl = BslL + tid * 8;
    floatx4 acc[4][2] = {};
    for (int k0 = 0; k0 < gK; k0 += 32) {
      gl_lds16(A_h + gArow + k0 + scs, ldsA);
      gl_lds16(A_m + gArow + k0 + scs, ldsAm);
      if (gnt == 3) gl_lds16(A_l + gArow + k0 + scs, ldsAl);
      gl_lds16(Wh + gBrow + k0 + scs, ldsB);
      gl_lds16(Wm + gBrow + k0 + scs, ldsBm);
      if (gnt == 3) gl_lds16(Wl + gBrow + k0 + scs, ldsBl);
      __syncthreads();
      short8 afh[4], afm[4], afl[4];
#pragma unroll
      for (int mi = 0; mi < 4; ++mi) {
        int rr = wm * 64 + mi * 16 + lm;
        int ro = rr * 32 + (((lane >> 4) ^ ((rr >> 1) & 3)) << 3);
        afh[mi] = *(const short8*)&AshL[ro];
        afm[mi] = *(const short8*)&AsmL[ro];
        if (gnt == 3) afl[mi] = *(const short8*)&AslL[ro];
      }
#pragma unroll
      for (int ni = 0; ni < 2; ++ni) {
        int rb = wn * 32 + ni * 16 + lm;
        int ro = rb * 32 + (((lane >> 4) ^ ((rb >> 1) & 3)) << 3);
        short8 bfh = *(const short8*)&BshL[ro];
        short8 bfm = *(const short8*)&BsmL[ro];
#pragma unroll
        for (int mi = 0; mi < 4; ++mi) {
          floatx4 a = acc[mi][ni];
          a = __builtin_amdgcn_mfma_f32_16x16x32_bf16(afh[mi], bfh, a, 0, 0, 0);
          a = __builtin_amdgcn_mfma_f32_16x16x32_bf16(afh[mi], bfm, a, 0, 0, 0);
          a = __builtin_amdgcn_mfma_f32_16x16x32_bf16(afm[mi], bfh, a, 0, 0, 0);
          if (gnt == 3) {
            short8 bfl = *(const short8*)&BslL[ro];
            a = __builtin_amdgcn_mfma_f32_16x16x32_bf16(afh[mi], bfl, a, 0, 0, 0);
            a = __builtin_amdgcn_mfma_f32_16x16x32_bf16(afl[mi], bfh, a, 0, 0, 0);
            a = __builtin_amdgcn_mfma_f32_16x16x32_bf16(afm[mi], bfm, a, 0, 0, 0);
          }
          acc[mi][ni] = a;
        }
      }
      __syncthreads();
    }
    int lr = (lane >> 4) * 4;
#pragma unroll
    for (int mi = 0; mi < 4; ++mi)
#pragma unroll
      for (int ni = 0; ni < 2; ++ni) {
        int colg = col0 + wn * 32 + ni * 16 + lm;
        if (colg >= gN) continue;
#pragma unroll
        for (int r = 0; r < 4; ++r) {
          int rowg = row0 + wm * 64 + mi * 16 + lr + r;
          C[(size_t)rowg * gN + colg] = acc[mi][ni][r];
        }
      }
  }
}

// ------------- fused degree head: xdeg = relu(relu(relu(X@W4+b4)@W5+b5)·w6+b6) -------------
__global__ __launch_bounds__(256) void degree_head_kernel(
    const short* __restrict__ Xh, const short* __restrict__ Xm,
    const short* __restrict__ W4h, const short* __restrict__ W4m, const float* __restrict__ b4,
    const short* __restrict__ W5h, const short* __restrict__ W5m, const float* __restrict__ b5,
    const float* __restrict__ w6, const float* __restrict__ b6,
    float* __restrict__ xdeg) {
  __shared__ __attribute__((aligned(16))) short Ash[32 * 40];
  __shared__ __attribute__((aligned(16))) short Asm[32 * 40];
  __shared__ __attribute__((aligned(16))) short Bsh[256 * 40];
  __shared__ __attribute__((aligned(16))) short Bsm[256 * 40];
  __shared__ __attribute__((aligned(16))) short H1h[32][264];
  __shared__ __attribute__((aligned(16))) short H1m[32][264];
  __shared__ float rowsum[32];
  int tid = threadIdx.x;
  int wave = tid >> 6, lane = tid & 63;
  int lm = lane & 15, g = lane >> 4, lk = g * 8;
  int row0 = blockIdx.x * 32;

  floatx4 acc[2][4] = {};
  for (int k0 = 0; k0 < 256; k0 += 32) {
    {
      int e = tid;
      int a = e >> 7, rem = e & 127;
      int r = rem >> 2, kc = (rem & 3) * 8;
      const short* src = a ? Xm : Xh;
      short* dst = a ? Asm : Ash;
      *(short8*)&dst[r * 40 + kc] = *(const short8*)&src[(size_t)(row0 + r) * 256 + k0 + kc];
    }
#pragma unroll
    for (int i = 0; i < 8; ++i) {
      int e = tid + i * 256;
      int a = e >> 10, rem = e & 1023;
      int r = rem >> 2, kc = (rem & 3) * 8;
      const short* src = a ? W4m : W4h;
      short* dst = a ? Bsm : Bsh;
      *(short8*)&dst[r * 40 + kc] = *(const short8*)&src[(size_t)r * 256 + k0 + kc];
    }
    __syncthreads();
    short8 afh[2], afm[2];
#pragma unroll
    for (int rt = 0; rt < 2; ++rt) {
      int ro = (rt * 16 + lm) * 40 + lk;
      afh[rt] = *(const short8*)&Ash[ro];
      afm[rt] = *(const short8*)&Asm[ro];
    }
#pragma unroll
    for (int ct = 0; ct < 4; ++ct) {
      int ro = (wave * 64 + ct * 16 + lm) * 40 + lk;
      short8 bfh = *(const short8*)&Bsh[ro];
      short8 bfm = *(const short8*)&Bsm[ro];
#pragma unroll
      for (int rt = 0; rt < 2; ++rt) {
        floatx4 a = acc[rt][ct];
        a = __builtin_amdgcn_mfma_f32_16x16x32_bf16(afh[rt], bfh, a, 0, 0, 0);
        a = __builtin_amdgcn_mfma_f32_16x16x32_bf16(afh[rt], bfm, a, 0, 0, 0);
        a = __builtin_amdgcn_mfma_f32_16x16x32_bf16(afm[rt], bfh, a, 0, 0, 0);
        acc[rt][ct] = a;
      }
    }
    __syncthreads();
  }
#pragma unroll
  for (int rt = 0; rt < 2; ++rt)
#pragma unroll
    for (int ct = 0; ct < 4; ++ct) {
      int col = wave * 64 + ct * 16 + lm;
      float bv = b4[col];
#pragma unroll
      for (int r = 0; r < 4; ++r) {
        int row = rt * 16 + g * 4 + r;
        float v = fmaxf(acc[rt][ct][r] + bv, 0.f);
        short hh = f2b(v);
        H1h[row][col] = hh;
        H1m[row][col] = f2b(v - b2f(hh));
      }
    }
  if (tid < 32) rowsum[tid] = 0.f;
  __syncthreads();

  floatx4 acc2[2][2] = {};
  for (int k0 = 0; k0 < 256; k0 += 32) {
#pragma unroll
    for (int i = 0; i < 4; ++i) {
      int e = tid + i * 256;
      int a = e >> 9, rem = e & 511;
      int r = rem >> 2, kc = (rem & 3) * 8;
      const short* src = a ? W5m : W5h;
      short* dst = a ? Bsm : Bsh;
      *(short8*)&dst[r * 40 + kc] = *(const short8*)&src[(size_t)r * 256 + k0 + kc];
    }
    __syncthreads();
    short8 afh[2], afm[2];
#pragma unroll
    for (int rt = 0; rt < 2; ++rt) {
      afh[rt] = *(const short8*)&H1h[rt * 16 + lm][k0 + lk];
      afm[rt] = *(const short8*)&H1m[rt * 16 + lm][k0 + lk];
    }
#pragma unroll
    for (int ct = 0; ct < 2; ++ct) {
      int ro = (wave * 32 + ct * 16 + lm) * 40 + lk;
      short8 bfh = *(const short8*)&Bsh[ro];
      short8 bfm = *(const short8*)&Bsm[ro];
#pragma unroll
      for (int rt = 0; rt < 2; ++rt) {
        floatx4 a = acc2[rt][ct];
        a = __builtin_amdgcn_mfma_f32_16x16x32_bf16(afh[rt], bfh, a, 0, 0, 0);
        a = __builtin_amdgcn_mfma_f32_16x16x32_bf16(afh[rt], bfm, a, 0, 0, 0);
        a = __builtin_amdgcn_mfma_f32_16x16x32_bf16(afm[rt], bfh, a, 0, 0, 0);
        acc2[rt][ct] = a;
      }
    }
    __syncthreads();
  }
#pragma unroll
  for (int rt = 0; rt < 2; ++rt) {
#pragma unroll
    for (int r = 0; r < 4; ++r) {
      float p = 0.f;
#pragma unroll
      for (int ct = 0; ct < 2; ++ct) {
        int col = wave * 32 + ct * 16 + lm;
        float v = fmaxf(acc2[rt][ct][r] + b5[col], 0.f);
        p += v * w6[col];
      }
#pragma unroll
      for (int off = 1; off < 16; off <<= 1) p += __shfl_xor(p, off, 64);
      if (lm == 0) atomicAdd(&rowsum[rt * 16 + g * 4 + r], p);
    }
  }
  __syncthreads();
  if (tid < 32) xdeg[row0 + tid] = fmaxf(rowsum[tid] + b6[0], 0.f);
}

// scalar edge agg (Hc not divisible by 4); AB is (rows x 2Hc)
__global__ void edge_agg_kernel(const float* __restrict__ AB, const float* __restrict__ bias,
                                const int* __restrict__ idx, int n, int Hc, int act,
                                int rows, int per,
                                float* __restrict__ out,
                                short* __restrict__ outh, short* __restrict__ outm,
                                short* __restrict__ outl) {
  int t = blockIdx.x * blockDim.x + threadIdx.x;
  if (t >= rows * Hc) return;
  int r = t / Hc, h = t - r * Hc;
  int d = r / per, rloc = r - d * per;
  int b = rloc / n;
  int s2 = 2 * Hc;
  float av = AB[(size_t)r * s2 + h] + bias[h];
  const int* ir = idx + ((size_t)d * per + rloc) * KNN_;
  int base = d * per + b * n;
  float m = -INFINITY;
  for (int k = 0; k < KNN_; ++k) {
    float v = av + AB[(size_t)(base + ir[k]) * s2 + Hc + h];
    v = fmaxf(v, 0.f);
    m = fmaxf(m, v);
  }
  if (act == 2) m = tanhf(m);
  if (out) out[t] = m;
  if (outh) {
    short hh, mm, ll;
    f2b3(m, hh, mm, ll);
    outh[t] = hh; outm[t] = mm;
    if (outl) outl[t] = ll;
  }
}

// vectorized edge agg: 4 features/thread, 8 rows/block (rows%8==0 required at call sites).
// Per-element FP order identical to scalar. Optional colsums: per-column double s/s2
// accumulated in registers over the block's 8 rows, LDS-reduced, one atomicAdd per column
// per block (replaces the uncoalesced bn_stats pass; double reassociation only).
__global__ __launch_bounds__(256) void edge_agg4_kernel(
    const float* __restrict__ AB, const float* __restrict__ bias,
    const int* __restrict__ idx, int n, int Hc, int act,
    int rows, int per,
    float* __restrict__ out,
    short* __restrict__ outh, short* __restrict__ outm, short* __restrict__ outl,
    double* __restrict__ colsums) {
  __shared__ double lds_s[4][256];
  __shared__ double lds_s2[4][256];
  int tid = threadIdx.x;
  int hq = tid & 63, rl = tid >> 6;
  int h = hq << 2;
  int s2s = 2 * Hc;
  double cs[4] = {0.0, 0.0, 0.0, 0.0}, cs2[4] = {0.0, 0.0, 0.0, 0.0};
#pragma unroll
  for (int sub = 0; sub < 2; ++sub) {
    int r = blockIdx.x * 8 + rl + sub * 4;
    if (r < rows) {
      int d = r / per, rloc = r - d * per;
      int b = rloc / n;
      float4 av = *(const float4*)&AB[(size_t)r * s2s + h];
      float4 bv = *(const float4*)&bias[h];
      float a0 = av.x + bv.x, a1 = av.y + bv.y, a2 = av.z + bv.z, a3 = av.w + bv.w;
      const int* ir = idx + ((size_t)d * per + rloc) * KNN_;
      int base = d * per + b * n;
      int nb[KNN_];
#pragma unroll
      for (int k = 0; k < KNN_; ++k) nb[k] = base + ir[k];
      float m0 = -INFINITY, m1 = -INFINITY, m2 = -INFINITY, m3 = -INFINITY;
#pragma unroll
      for (int k = 0; k < KNN_; ++k) {
        float4 bb = *(const float4*)&AB[(size_t)nb[k] * s2s + Hc + h];
        m0 = fmaxf(m0, fmaxf(a0 + bb.x, 0.f));
        m1 = fmaxf(m1, fmaxf(a1 + bb.y, 0.f));
        m2 = fmaxf(m2, fmaxf(a2 + bb.z, 0.f));
        m3 = fmaxf(m3, fmaxf(a3 + bb.w, 0.f));
      }
      if (act == 2) { m0 = tanhf(m0); m1 = tanhf(m1); m2 = tanhf(m2); m3 = tanhf(m3); }
      size_t o = (size_t)r * Hc + h;
      if (out) *(float4*)&out[o] = make_float4(m0, m1, m2, m3);
      if (outh) {
        short h0, mm0, l0, h1, mm1, l1, h2, mm2, l2, h3, mm3, l3;
        f2b3(m0, h0, mm0, l0); f2b3(m1, h1, mm1, l1);
        f2b3(m2, h2, mm2, l2); f2b3(m3, h3, mm3, l3);
        short4v vh = {h0, h1, h2, h3};
        short4v vm = {mm0, mm1, mm2, mm3};
        *(short4v*)&outh[o] = vh;
        *(short4v*)&outm[o] = vm;
        if (outl) {
          short4v vl = {l0, l1, l2, l3};
          *(short4v*)&outl[o] = vl;
        }
      }
      if (colsums) {
        double d0 = (double)m0, d1 = (double)m1, d2 = (double)m2, d3 = (double)m3;
        cs[0] += d0; cs2[0] += d0 * d0;
        cs[1] += d1; cs2[1] += d1 * d1;
        cs[2] += d2; cs2[2] += d2 * d2;
        cs[3] += d3; cs2[3] += d3 * d3;
      }
    }
  }
  if (colsums) {
#pragma unroll
    for (int j = 0; j < 4; ++j) {
      lds_s[rl][h + j] = cs[j];
      lds_s2[rl][h + j] = cs2[j];
    }
    __syncthreads();
    int c = tid;
    double ss = ((lds_s[0][c] + lds_s[1][c]) + lds_s[2][c]) + lds_s[3][c];
    double ss2 = ((lds_s2[0][c] + lds_s2[1][c]) + lds_s2[2][c]) + lds_s2[3][c];
    atomicAdd(&colsums[c], ss);
    atomicAdd(&colsums[256 + c], ss2);
  }
}

// -------- fused sag select + pool + readout (+gtpred pass-through, +classifier) ----
// 1024 threads (16 waves). scsh computed in-block from colsums (bn_stats formula) into LDS.
// ys rowdot per-row FP order exact; pool r-loop split over 4 groups (mx exact, sm fixed
// reassociation). dinv/gcn/topk unchanged (exact selection semantics).
__global__ __launch_bounds__(1024) void sag_pool_kernel(
    const float* __restrict__ t1,
    const double* __restrict__ colsums, const float* __restrict__ bng,
    const float* __restrict__ bnb, int M,
    const float* __restrict__ pw,
    const float* __restrict__ adj_in, int n, int k,
    const float* __restrict__ pb,
    int* __restrict__ perm, float* __restrict__ adjp,
    const float* __restrict__ deg, const float* __restrict__ xdeg,
    float* __restrict__ gt, float* __restrict__ pred,
    const int* __restrict__ gperm, int gk, float* __restrict__ ggt, float* __restrict__ gpred,
    const int* __restrict__ remap, int accum,
    short* __restrict__ xph, short* __restrict__ xpm, short* __restrict__ xpl,
    short* __restrict__ soh, short* __restrict__ som, float* __restrict__ z,
    const float* __restrict__ W1, const float* __restrict__ b1,
    const float* __restrict__ W2, const float* __restrict__ b2,
    const float* __restrict__ W3, const float* __restrict__ b3,
    float* __restrict__ probs) {
  __shared__ float ys[40], dinv[40], scs[40], tant[40];
  __shared__ int locs[40];
  __shared__ __attribute__((aligned(16))) float scshL[512];
  __shared__ __attribute__((aligned(16))) float pmx[4][256];
  __shared__ __attribute__((aligned(16))) float psm[4][256];
  __shared__ __attribute__((aligned(16))) float ca[512];
  __shared__ __attribute__((aligned(16))) float z1s[256];
  __shared__ __attribute__((aligned(16))) float z2s[128];
  __shared__ float lg[2];
  int b = blockIdx.x;
  int i = threadIdx.x;
  int wave = i >> 6, lane = i & 63;
  if (i < 256) {   // bn finalize (exact bn_stats formula)
    double mean = colsums[i] / M;
    double var = colsums[256 + i] / M - mean * mean;
    float rstd = 1.f / sqrtf((float)var + 1e-5f);
    float sc = rstd * bng[i];
    scshL[i] = sc;
    scshL[256 + i] = bnb[i] - (float)mean * sc;
  }
  __syncthreads();
  // ys rowdot: 16 waves, per-row FP order identical to original
  for (int row = wave; row < n; row += 16) {
    const float* xr = t1 + (size_t)(b * n + row) * H_;
    float s = 0.f;
    for (int kk = lane; kk < H_; kk += 64) {
      float v = fmaxf(xr[kk] * scshL[kk] + scshL[H_ + kk], 0.f);
      s += v * pw[kk];
    }
    for (int off = 32; off; off >>= 1) s += __shfl_down(s, off, 64);
    if (lane == 0) ys[row] = s;
  }
  __syncthreads();
  if (i < n) {
    const float* ar = adj_in + ((size_t)b * n + i) * n;
    float sum = 1.f;
    for (int j = 0; j < n; ++j) sum += ar[j];
    dinv[i] = 1.f / sqrtf(sum);
  }
  __syncthreads();
  if (i < n) {
    const float* ar = adj_in + ((size_t)b * n + i) * n;
    float acc = 0.f;
    for (int j = 0; j < n; ++j) {
      float a = ar[j] + (i == j ? 1.f : 0.f);
      acc += a * dinv[j] * ys[j];
    }
    scs[i] = dinv[i] * acc + pb[0];
  }
  __syncthreads();
  if (i < n) {   // rank-based stable descending top-k (ties -> lowest index)
    float si = scs[i];
    int rank = 0;
    for (int j = 0; j < n; ++j) {
      float sj = scs[j];
      rank += (sj > si || (sj == si && j < i)) ? 1 : 0;
    }
    if (rank < k) {
      tant[rank] = tanhf(si);
      locs[rank] = i;
      perm[b * k + rank] = b * n + i;
    }
  }
  __syncthreads();
  if (adjp) {
    for (int e = threadIdx.x; e < k * k; e += 1024) {
      int t1i = e / k, t2i = e - t1i * k;
      adjp[(size_t)b * k * k + e] = adj_in[((size_t)b * n + locs[t1i]) * n + locs[t2i]];
    }
  }
  if (gt && threadIdx.x < k) {
    int p = b * n + locs[threadIdx.x];
    gt[b * k + threadIdx.x] = deg[p];
    pred[b * k + threadIdx.x] = xdeg[p];
  }
  if (ggt && threadIdx.x < gk) {     // previous level's gtpred (graph-local)
    int p = gperm[b * gk + threadIdx.x];
    ggt[b * gk + threadIdx.x] = deg[p];
    gpred[b * gk + threadIdx.x] = xdeg[p];
  }
  // ---- pool + readout: r-loop split across 4 groups of 256 threads ----
  int hc = i & 255;
  int rg = i >> 8;                   // 0..3
  float sc = scshL[hc], sh = scshL[H_ + hc];
  float mx = -INFINITY, sm = 0.f;
  for (int r = rg; r < k; r += 4) {
    int loc = locs[r];
    float tg = tant[r];
    int own = b * n + loc;
    float v = fmaxf(t1[(size_t)own * H_ + hc] * sc + sh, 0.f) * tg;
    short hh, mm, ll;
    f2b3(v, hh, mm, ll);
    size_t xo = ((size_t)(b * k + r)) * H_ + hc;
    xph[xo] = hh; xpm[xo] = mm; xpl[xo] = ll;
    int tgt = remap ? remap[own] : own;
    size_t so = (size_t)tgt * H_ + hc;
    soh[so] = hh; som[so] = mm;
    float vq = b2f(hh) + b2f(mm) + b2f(ll);
    mx = fmaxf(mx, vq);
    sm += vq;
  }
  pmx[rg][hc] = mx;
  psm[rg][hc] = sm;
  __syncthreads();
  if (i < 256) {
    float m0 = fmaxf(fmaxf(pmx[0][hc], pmx[1][hc]), fmaxf(pmx[2][hc], pmx[3][hc]));
    float s0 = ((psm[0][hc] + psm[1][hc]) + psm[2][hc]) + psm[3][hc];
    float* zb = z + (size_t)b * 2 * H_;
    float mean = s0 / (float)k;
    float zr1, zr2;
    if (accum) { zr1 = zb[hc] + m0; zr2 = zb[H_ + hc] + mean; zb[hc] = zr1; zb[H_ + hc] = zr2; }
    else       { zr1 = m0;  zr2 = mean; zb[hc] = zr1; zb[H_ + hc] = zr2; }
    if (probs) { ca[hc] = zr1; ca[H_ + hc] = zr2; }
  }
  // ---- classifier phase (final level only): identical values/order to before ----
  if (probs) {
    __syncthreads();
    if (i < 256) {  // layer 1: N=256, K=512, relu
      int c = hc;
      float s = 0.f;
      for (int kk = 0; kk < 512; kk += 4) {
        float4 av = *(const float4*)&ca[kk];
        s += av.x * W1[(size_t)kk * 256 + c];
        s += av.y * W1[(size_t)(kk + 1) * 256 + c];
        s += av.z * W1[(size_t)(kk + 2) * 256 + c];
        s += av.w * W1[(size_t)(kk + 3) * 256 + c];
      }
      z1s[c] = fmaxf(s + b1[c], 0.f);
    }
    __syncthreads();
    if (i < 128) {  // layer 2: N=128, K=256, relu
      int c = i;
      float s = 0.f;
      for (int kk = 0; kk < 256; kk += 4) {
        float4 av = *(const float4*)&z1s[kk];
        s += av.x * W2[(size_t)kk * 128 + c];
        s += av.y * W2[(size_t)(kk + 1) * 128 + c];
        s += av.z * W2[(size_t)(kk + 2) * 128 + c];
        s += av.w * W2[(size_t)(kk + 3) * 128 + c];
      }
      z2s[c] = fmaxf(s + b2[c], 0.f);
    }
    __syncthreads();
    if (wave < 2) {   // layer 3: N=2, K=128 (wavedot order)
      float s = 0.f;
      for (int kk = lane; kk < 128; kk += 64) s += z2s[kk] * W3[(size_t)kk * 2 + wave];
      for (int off = 32; off; off >>= 1) s += __shfl_down(s, off, 64);
      if (lane == 0) lg[wave] = s + b3[wave];
    }
    __syncthreads();
    if (i == 0) {
      float aa = lg[0], cc = lg[1];
      float m = fmaxf(aa, cc);
      float ea = expf(aa - m), ec = expf(cc - m);
      float inv = 1.f / (ea + ec);
      probs[2 * b] = ea * inv;
      probs[2 * b + 1] = ec * inv;
    }
  }
}

extern "C" void kernel_launch(void* const* d_in, const int* in_sizes, int n_in,
                              void* d_out, int out_size, void* d_ws, size_t ws_size,
                              hipStream_t stream) {
  auto in = [&](int i) { return (const float*)d_in[i]; };
  const float* x      = in(0);
  const float* adj    = in(1);
  const float* w_mlp1 = in(2);  const float* b_mlp1 = in(3);
  const float* w_mlp2 = in(4);  const float* b_mlp2 = in(5);
  const float* w_mlp3 = in(6);  const float* b_mlp3 = in(7);
  const float* w_mlp6 = in(8);  const float* b_mlp6 = in(9);
  const float* bn1_g = in(10);  const float* bn1_b = in(11);
  const float* bn2_g = in(12);  const float* bn2_b = in(13);
  const float* bn3_g = in(14);  const float* bn3_b = in(15);
  const float* p1_w = in(16);   const float* p1_b = in(17);
  const float* p2_w = in(18);   const float* p2_b = in(19);
  const float* p3_w = in(20);   const float* p3_b = in(21);
  const float* lin1_w = in(22); const float* lin1_b = in(23);
  const float* lin2_w = in(24); const float* lin2_b = in(25);
  const float* lin3_w = in(26); const float* lin3_b = in(27);
  const float* lin4_w = in(28); const float* lin4_b = in(29);
  const float* lin5_w = in(30); const float* lin5_b = in(31);
  const float* lin6_w = in(32); const float* lin6_b = in(33);

  float* out = (float*)d_out;
  float* out_probs = out;
  float* out_dec1  = out_probs + 256;            // 3 x 4992*39 contiguous
  float* out_gt1   = out_dec1 + 3 * 4992 * 39;
  float* out_pred1 = out_gt1 + 4096;
  float* out_gt2   = out_pred1 + 4096;
  float* out_pred2 = out_gt2 + 3328;
  float* out_gt3   = out_pred2 + 3328;
  float* out_pred3 = out_gt3 + 2688;

  char* base = (char*)d_ws;
  size_t off = 0;
  auto allocf = [&](size_t n) -> float* {
    float* p = (float*)(base + off);
    off += ((n * sizeof(float) + 255) & ~(size_t)255);
    return p;
  };
  auto alloci = [&](size_t n) -> int* {
    int* p = (int*)(base + off);
    off += ((n * sizeof(int) + 255) & ~(size_t)255);
    return p;
  };
  auto allocs = [&](size_t n) -> short* {
    short* p = (short*)(base + off);
    off += ((n * sizeof(short) + 255) & ~(size_t)255);
    return p;
  };
  auto allocd = [&](size_t n) -> double* {
    double* p = (double*)(base + off);
    off += ((n * sizeof(double) + 255) & ~(size_t)255);
    return p;
  };

  const size_t S = (size_t)4992 * 256;
  const size_t AB_S = (size_t)4992 * 512;
  const int SI = 4992 * KNN_;

  short* wt1h = allocs(512 * 64); short* wt1m = allocs(512 * 64); short* wt1l = allocs(512 * 64);
  short* wt2h = allocs(512 * 256); short* wt2m = allocs(512 * 256); short* wt2l = allocs(512 * 256);
  short* wt3h = allocs(512 * 256); short* wt3m = allocs(512 * 256); short* wt3l = allocs(512 * 256);
  short* wt6h = allocs(78 * 256);  short* wt6m = allocs(78 * 256);
  short* l4h = allocs(256 * 256);  short* l4m = allocs(256 * 256);
  short* l5h = allocs(128 * 256);  short* l5m = allocs(128 * 256);
  short* xsph = allocs(4992 * 64); short* xspm = allocs(4992 * 64); short* xspl = allocs(4992 * 64);
  float* deg  = allocf(4992);
  float* xdeg = allocf(4992);
  int* idxb = alloci(3 * SI);
  float* AB3 = allocf(3 * AB_S);
  float* trunk_t1 = allocf(S);
  double* bnsum = allocd(3 * 512);
  short* xph = allocs((size_t)4096 * 256); short* xpm = allocs((size_t)4096 * 256); short* xpl = allocs((size_t)4096 * 256);
  short* xoutb_h = allocs(3 * S);
  short* xoutb_m = allocs(3 * S);
  short* t1b_h = allocs(3 * S);
  short* t1b_m = allocs(3 * S);
  float* adj1 = allocf(128 * 32 * 32);
  float* adj2 = allocf(128 * 26 * 26);
  int* perm1 = alloci(4096); int* perm2 = alloci(3328); int* perm3 = alloci(2688);
  float* z  = allocf(128 * 512);
  if (off > ws_size) return;

  // t2b aliases xoutb (dead after decoder stage 1)
  short* t2b_h = xoutb_h; short* t2b_m = xoutb_m;

  const size_t LDS3 = 6 * 128 * 32 * sizeof(short);          // 49152: 3-term gemm (>= knn 21.2KB)
  const size_t LDS2 = 4 * 128 * 32 * sizeof(short);          // 32768: 2-term gemm (>= knn 17.3KB)

  // ---- prep (incl. xoutb zeroing task 8 + bnsum zeroing task 9) ----
  prep_kernel<<<6627, 256, 0, stream>>>(
      w_mlp1, w_mlp2, w_mlp3, w_mlp6, lin4_w, lin5_w, x, adj,
      wt1h, wt1m, wt1l, wt2h, wt2m, wt2l, wt3h, wt3m, wt3l, wt6h, wt6m,
      l4h, l4m, l5h, l5m, xsph, xspm, xspl, deg, xoutb_h, bnsum);

  // ---- level 1: fused knn+gemm, then agg(+bn sums)/sag+pool ----
  knn_gemm_kernel<<<B_ + 4 * 39, 512, LDS3, stream>>>(
      xsph, xspm, xspl, 3, 64, N_, 64, idxb, B_,
      xsph, xspm, xspl, 3, 64, wt1h, wt1m, wt1l, AB3, 4992, 512, 39, 0, 0);
  edge_agg4_kernel<<<4992 / 8, 256, 0, stream>>>(AB3, b_mlp1, idxb, N_, 256, 0, 4992, 4992,
                                                 trunk_t1, nullptr, nullptr, nullptr, bnsum);
  sag_pool_kernel<<<B_, 1024, 0, stream>>>(
      trunk_t1, bnsum, bn1_g, bn1_b, 4992, p1_w, adj, N_, K1_, p1_b,
      perm1, adj1, nullptr, nullptr, nullptr, nullptr,
      nullptr, 0, nullptr, nullptr,
      nullptr, 0, xph, xpm, xpl, xoutb_h, xoutb_m, z,
      nullptr, nullptr, nullptr, nullptr, nullptr, nullptr, nullptr);
  // ---- degree head from x_out1 ----
  degree_head_kernel<<<156, 256, 0, stream>>>(
      xoutb_h, xoutb_m, l4h, l4m, lin4_b, l5h, l5m, lin5_b, lin6_w, lin6_b, xdeg);

  // ---- level 2 (also emits level-1 gt/pred via graph-local gather) ----
  knn_gemm_kernel<<<B_ + 4 * 32, 512, LDS3, stream>>>(
      xph, xpm, xpl, 3, 256, K1_, 256, idxb, B_,
      xph, xpm, xpl, 3, 256, wt2h, wt2m, wt2l, AB3, 4096, 512, 32, 0, 0);
  edge_agg4_kernel<<<4096 / 8, 256, 0, stream>>>(AB3, b_mlp2, idxb, K1_, 256, 0, 4096, 4096,
                                                 trunk_t1, nullptr, nullptr, nullptr, bnsum + 512);
  sag_pool_kernel<<<B_, 1024, 0, stream>>>(
      trunk_t1, bnsum + 512, bn2_g, bn2_b, 4096, p2_w, adj1, K1_, K2_, p2_b,
      perm2, adj2, deg, xdeg, out_gt2, out_pred2,
      perm1, K1_, out_gt1, out_pred1,
      perm1, 1, xph, xpm, xpl, xoutb_h + S, xoutb_m + S, z,
      nullptr, nullptr, nullptr, nullptr, nullptr, nullptr, nullptr);

  // ---- level 3 (+ fused classifier on final z) ----
  knn_gemm_kernel<<<B_ + 4 * 26, 512, LDS3, stream>>>(
      xph, xpm, xpl, 3, 256, K2_, 256, idxb, B_,
      xph, xpm, xpl, 3, 256, wt3h, wt3m, wt3l, AB3, 3328, 512, 26, 0, 0);
  edge_agg4_kernel<<<3328 / 8, 256, 0, stream>>>(AB3, b_mlp3, idxb, K2_, 256, 0, 3328, 3328,
                                                 trunk_t1, nullptr, nullptr, nullptr, bnsum + 1024);
  sag_pool_kernel<<<B_, 1024, 0, stream>>>(
      trunk_t1, bnsum + 1024, bn3_g, bn3_b, 3328, p3_w, adj2, K2_, K3_, p3_b,
      perm3, nullptr, deg, xdeg, out_gt3, out_pred3,
      nullptr, 0, nullptr, nullptr,
      perm2, 1, xph, xpm, xpl, xoutb_h + 2 * S, xoutb_m + 2 * S, z,
      lin1_w, lin1_b, lin2_w, lin2_b, lin3_w, lin3_b, out_probs);

  // ---- batched decoders (3 independent; fused knn+gemm per stage) ----
  // stage 1: wcat3, tanh
  knn_gemm_kernel<<<3 * B_ + 4 * 39 * 3, 512, LDS2, stream>>>(
      xoutb_h, xoutb_m, nullptr, 2, 256, N_, 256, idxb, 3 * B_,
      xoutb_h, xoutb_m, nullptr, 2, 256, wt3h, wt3m, nullptr, AB3, 4992, 512, 39, S, AB_S);
  edge_agg4_kernel<<<3 * 4992 / 8, 256, 0, stream>>>(
      AB3, b_mlp3, idxb, N_, 256, 2, 3 * 4992, 4992, nullptr, t1b_h, t1b_m, nullptr, nullptr);
  // stage 2: wcat2, tanh
  knn_gemm_kernel<<<3 * B_ + 4 * 39 * 3, 512, LDS2, stream>>>(
      t1b_h, t1b_m, nullptr, 2, 256, N_, 256, idxb, 3 * B_,
      t1b_h, t1b_m, nullptr, 2, 256, wt2h, wt2m, nullptr, AB3, 4992, 512, 39, S, AB_S);
  edge_agg4_kernel<<<3 * 4992 / 8, 256, 0, stream>>>(
      AB3, b_mlp2, idxb, N_, 256, 2, 3 * 4992, 4992, nullptr, t2b_h, t2b_m, nullptr, nullptr);
  // stage 3: wcat6, linear -> out_dec (Hc=39 not divisible by 4 -> scalar)
  knn_gemm_kernel<<<3 * B_ + 1 * 39 * 3, 512, LDS2, stream>>>(
      t2b_h, t2b_m, nullptr, 2, 256, N_, 256, idxb, 3 * B_,
      t2b_h, t2b_m, nullptr, 2, 256, wt6h, wt6m, nullptr, AB3, 4992, 78, 39, S, (size_t)4992 * 78);
  edge_agg_kernel<<<cdiv(3 * 4992 * 39, 256), 256, 0, stream>>>(
      AB3, b_mlp6, idxb, N_, 39, 0, 3 * 4992, 4992, out_dec1, nullptr, nullptr, nullptr);
}

// Round 17
// 428.698 us; speedup vs baseline: 1.0144x; 1.0144x over previous
//
#include <hip/hip_runtime.h>
#include <cmath>

#define B_   128
#define N_   39
#define KNN_ 10
#define H_   256
#define K1_  32
#define K2_  26
#define K3_  21

static inline int cdiv(int a, int b) { return (a + b - 1) / b; }

typedef __attribute__((ext_vector_type(8))) short short8;
typedef __attribute__((ext_vector_type(4))) short short4v;
typedef __attribute__((ext_vector_type(4))) float floatx4;

__device__ inline short f2b(float f) {   // fp32 -> bf16 RNE
  unsigned u = __float_as_uint(f);
  u += 0x7fff + ((u >> 16) & 1);
  return (short)(u >> 16);
}
__device__ inline float b2f(short h) {
  return __uint_as_float(((unsigned)(unsigned short)h) << 16);
}
__device__ inline void f2b3(float v, short& h, short& m, short& l) {  // v ~= h+m+l (24 bits)
  h = f2b(v);
  float r1 = v - b2f(h);
  m = f2b(r1);
  l = f2b(r1 - b2f(m));
}

// async global->LDS 16B (dest is wave-uniform base + lane*16: pass lane-linear ptr)
__device__ __forceinline__ void gl_lds16(const short* g, short* l) {
  __builtin_amdgcn_global_load_lds(
      (const __attribute__((address_space(1))) unsigned int*)g,
      (__attribute__((address_space(3))) unsigned int*)l, 16, 0, 0);
}

// ------------- one-shot prep (flattened 1-D grid, exact per-task block ranges) -------------
// task 8: zero xoutb scatter targets; task 9: zero bn column-sum accumulators.
__global__ void prep_kernel(
    const float* __restrict__ w1, const float* __restrict__ w2,
    const float* __restrict__ w3, const float* __restrict__ w6,
    const float* __restrict__ l4, const float* __restrict__ l5,
    const float* __restrict__ x, const float* __restrict__ adj,
    short* __restrict__ wt1h, short* __restrict__ wt1m, short* __restrict__ wt1l,
    short* __restrict__ wt2h, short* __restrict__ wt2m, short* __restrict__ wt2l,
    short* __restrict__ wt3h, short* __restrict__ wt3m, short* __restrict__ wt3l,
    short* __restrict__ wt6h, short* __restrict__ wt6m,
    short* __restrict__ l4h, short* __restrict__ l4m,
    short* __restrict__ l5h, short* __restrict__ l5m,
    short* __restrict__ xsph, short* __restrict__ xspm, short* __restrict__ xspl,
    float* __restrict__ deg, short* __restrict__ zbase, double* __restrict__ bnsum) {
  int blk = blockIdx.x;
  int task, base;
  if      (blk < 128)  { task = 0; base = 0; }
  else if (blk < 640)  { task = 1; base = 128; }
  else if (blk < 1152) { task = 2; base = 640; }
  else if (blk < 1230) { task = 3; base = 1152; }
  else if (blk < 1486) { task = 4; base = 1230; }
  else if (blk < 1614) { task = 5; base = 1486; }
  else if (blk < 2862) { task = 6; base = 1614; }
  else if (blk < 2882) { task = 7; base = 2862; }
  else if (blk < 6626) { task = 8; base = 2882; }
  else                 { task = 9; base = 6626; }
  int t = (blk - base) * 256 + threadIdx.x;
  if (task == 0) {            // wcat1 tripleT: [512][64], K=39 padded
    if (t >= 512 * 64) return;
    int nn = t >> 6, k = t & 63;
    float v = 0.f;
    if (k < 39) v = (nn < 256) ? w1[k * 256 + nn] - w1[(39 + k) * 256 + nn]
                               : w1[(39 + k) * 256 + (nn - 256)];
    short h, m, l; f2b3(v, h, m, l);
    wt1h[t] = h; wt1m[t] = m; wt1l[t] = l;
  } else if (task == 1) {     // wcat2 tripleT: [512][256]
    if (t >= 512 * 256) return;
    int nn = t >> 8, k = t & 255;
    float v = (nn < 256) ? w2[k * 256 + nn] - w2[(256 + k) * 256 + nn]
                         : w2[(256 + k) * 256 + (nn - 256)];
    short h, m, l; f2b3(v, h, m, l);
    wt2h[t] = h; wt2m[t] = m; wt2l[t] = l;
  } else if (task == 2) {     // wcat3 tripleT
    if (t >= 512 * 256) return;
    int nn = t >> 8, k = t & 255;
    float v = (nn < 256) ? w3[k * 256 + nn] - w3[(256 + k) * 256 + nn]
                         : w3[(256 + k) * 256 + (nn - 256)];
    short h, m, l; f2b3(v, h, m, l);
    wt3h[t] = h; wt3m[t] = m; wt3l[t] = l;
  } else if (task == 3) {     // wcat6 T (h,m): [78][256]
    if (t >= 78 * 256) return;
    int nn = t >> 8, k = t & 255;
    float v = (nn < 39) ? w6[k * 39 + nn] - w6[(256 + k) * 39 + nn]
                        : w6[(256 + k) * 39 + (nn - 39)];
    short h, m, l; f2b3(v, h, m, l);
    wt6h[t] = h; wt6m[t] = m;
  } else if (task == 4) {     // lin4 T (h,m): [256][256]
    if (t >= 256 * 256) return;
    int nn = t >> 8, k = t & 255;
    short h, m, l; f2b3(l4[k * 256 + nn], h, m, l);
    l4h[t] = h; l4m[t] = m;
  } else if (task == 5) {     // lin5 T (h,m): [128][256]
    if (t >= 128 * 256) return;
    int nn = t >> 8, k = t & 255;
    short h, m, l; f2b3(l5[k * 128 + nn], h, m, l);
    l5h[t] = h; l5m[t] = m;
  } else if (task == 6) {     // x split: [4992][64], F=39 padded
    if (t >= 4992 * 64) return;
    int r = t >> 6, k = t & 63;
    float v = (k < 39) ? x[r * 39 + k] : 0.f;
    short h, m, l; f2b3(v, h, m, l);
    xsph[t] = h; xspm[t] = m; xspl[t] = l;
  } else if (task == 7) {     // degree
    if (t >= B_ * N_) return;
    const float* row = adj + (size_t)t * N_;
    float s = 0.f;
    for (int j = 0; j < N_; ++j) s += row[j];
    deg[t] = s;
  } else if (task == 8) {     // zero xoutb (958464 x 16B chunks)
    if (t >= 958464) return;
    short8 zz = {};
    *(short8*)&zbase[(size_t)t * 8] = zz;
  } else {                    // zero bn sums: 3 levels x 512 doubles
    if (t >= 256) return;
    for (int j = 0; j < 6; ++j) bnsum[t + j * 256] = 0.0;
  }
}

// ======== fused KNN + GEMM (one dispatch; block role by blockIdx.x) ========
// knn: blocks [0, knnB): MFMA gram + rank-parallel KNN (per graph); register staging.
// gemm: blocks [knnB, ...): C = A·W^T via global_load_lds width-16 staging into unpadded
// [128][32] tiles with XOR chunk swizzle c' = c ^ ((row>>1)&3).
// gemm work index is XCD-chunk-swizzled (m204 bijection, knnB%8==0).
// M%128==0 required; store guard on N. Both paths 512 thr. nterms via gnt (2/3-term split).
__global__ __launch_bounds__(512) void knn_gemm_kernel(
    const short* __restrict__ kxh, const short* __restrict__ kxm, const short* __restrict__ kxl,
    int knt, int kKs, int kn, int kF32, int* __restrict__ idx, int knnB,
    const short* __restrict__ Ah, const short* __restrict__ Am, const short* __restrict__ Al,
    int gnt, int gK,
    const short* __restrict__ Wh, const short* __restrict__ Wm, const short* __restrict__ Wl,
    float* __restrict__ C0, int gM, int gN, int gyB,
    size_t Astride, size_t Cstride) {
  extern __shared__ char smem[];
  int tid = threadIdx.x;
  int wave = tid >> 6, lane = tid & 63;
  int lm = lane & 15, lk = (lane >> 4) * 8;
  if ((int)blockIdx.x < knnB) {
    // ---------------- KNN path (register staging) ----------------
    short* sh_h = (short*)smem;
    short* sh_m = sh_h + 48 * 40;
    short* sh_l = sh_m + 48 * 40;
    float* Gs   = (float*)(sh_l + 48 * 40);    // [48][49]
    float* diag = Gs + 48 * 49;
    int b = blockIdx.x;
    int nt = (kn + 15) >> 4;
    int tasks = nt * nt;
    floatx4 acc[2] = {};
    int stage_elems = 384 * knt;
    for (int k0 = 0; k0 < kF32; k0 += 32) {
      for (int e = tid; e < stage_elems; e += 512) {
        int a = e / 384, rem = e - a * 384;
        int r = rem >> 3, c4 = (rem & 7) * 4;
        const short* src = (a == 0) ? kxh : (a == 1) ? kxm : kxl;
        short* dst = (a == 0) ? sh_h : (a == 1) ? sh_m : sh_l;
        *(short4v*)&dst[r * 40 + c4] =
            *(const short4v*)&src[((size_t)(b * kn + r)) * kKs + k0 + c4];
      }
      __syncthreads();
#pragma unroll
      for (int ai = 0; ai < 2; ++ai) {
        int t = wave + ai * 8;
        if (t < tasks) {
          int ti = t / nt, tj = t - ti * nt;
          int ra = (ti * 16 + lm) * 40 + lk;
          int rb = (tj * 16 + lm) * 40 + lk;
          short8 ah = *(const short8*)&sh_h[ra];
          short8 am = *(const short8*)&sh_m[ra];
          short8 bh = *(const short8*)&sh_h[rb];
          short8 bm = *(const short8*)&sh_m[rb];
          floatx4 a = acc[ai];
          a = __builtin_amdgcn_mfma_f32_16x16x32_bf16(ah, bh, a, 0, 0, 0);
          a = __builtin_amdgcn_mfma_f32_16x16x32_bf16(ah, bm, a, 0, 0, 0);
          a = __builtin_amdgcn_mfma_f32_16x16x32_bf16(am, bh, a, 0, 0, 0);
          if (knt == 3) {
            short8 al = *(const short8*)&sh_l[ra];
            short8 bl = *(const short8*)&sh_l[rb];
            a = __builtin_amdgcn_mfma_f32_16x16x32_bf16(ah, bl, a, 0, 0, 0);
            a = __builtin_amdgcn_mfma_f32_16x16x32_bf16(al, bh, a, 0, 0, 0);
            a = __builtin_amdgcn_mfma_f32_16x16x32_bf16(am, bm, a, 0, 0, 0);
          }
          acc[ai] = a;
        }
      }
      __syncthreads();
    }
#pragma unroll
    for (int ai = 0; ai < 2; ++ai) {
      int t = wave + ai * 8;
      if (t < tasks) {
        int ti = t / nt, tj = t - ti * nt;
        int col = tj * 16 + lm;
        int rbase = ti * 16 + (lane >> 4) * 4;
#pragma unroll
        for (int r = 0; r < 4; ++r) Gs[(rbase + r) * 49 + col] = acc[ai][r];
      }
    }
    __syncthreads();
    if (tid < 48) diag[tid] = (tid < kn) ? Gs[tid * 49 + tid] : INFINITY;
    __syncthreads();
    for (int row = wave; row < kn; row += 8) {
      float gii = diag[row];
      float dj = (lane < kn) ? (gii + diag[lane] - 2.f * Gs[row * 49 + lane]) : INFINITY;
      int rank = 0;
      for (int j = 0; j < kn; ++j) {
        float djp = gii + diag[j] - 2.f * Gs[row * 49 + j];
        rank += (djp < dj || (djp == dj && j < lane)) ? 1 : 0;
      }
      if (lane < kn && rank < KNN_)
        idx[(size_t)(b * kn + row) * KNN_ + rank] = lane;
    }
  } else {
    // ---------------- GEMM path: global_load_lds staging + XOR chunk swizzle ----------------
    short* AshL = (short*)smem;                 // [128][32] per term (8192 B each)
    short* AsmL = AshL + 4096;
    short* AslL = AsmL + 4096;
    short* BshL = (short*)smem + gnt * 4096;
    short* BsmL = BshL + 4096;
    short* BslL = BsmL + 4096;
    int gb = blockIdx.x - knnB;
    int gxB = (gN + 127) >> 7;
    // m204 bijective XCD chunk swizzle: xcd = gb&7 (knnB%8==0), j-th block on that xcd
    int nb = (int)gridDim.x - knnB;
    int xcd = gb & 7, j = gb >> 3;
    int q8 = nb >> 3, r8 = nb & 7;
    int work = (xcd < r8 ? xcd * (q8 + 1) : r8 * (q8 + 1) + (xcd - r8) * q8) + j;
    int gx = work % gxB;
    int rest = work / gxB;
    int gy = rest % gyB;
    int gz = rest / gyB;
    const short* A_h = Ah + (size_t)gz * Astride;
    const short* A_m = Am ? Am + (size_t)gz * Astride : nullptr;
    const short* A_l = Al ? Al + (size_t)gz * Astride : nullptr;
    float* C = C0 + (size_t)gz * Cstride;
    int row0 = gy * 128, col0 = gx * 128;
    int wm = wave & 1, wn = wave >> 1;
    // staging coords: thread tid -> LDS chunk (row=tid>>2, c=tid&3); source chunk c^((row>>1)&3)
    int srow = tid >> 2;
    int scs = ((tid & 3) ^ ((srow >> 1) & 3)) << 3;   // swizzled source offset (shorts)
    size_t gArow = (size_t)(row0 + srow) * gK;
    size_t gBrow = (size_t)(col0 + srow) * gK;
    short* ldsA = AshL + tid * 8;   // lane-linear dests (16 B per lane)
    short* ldsAm = AsmL + tid * 8;
    short* ldsAl = AslL + tid * 8;
    short* ldsB = BshL + tid * 8;
    short* ldsBm = BsmL + tid * 8;
    short* ldsBl = BslL + tid * 8;
    floatx4 acc[4][2] = {};
    for (int k0 = 0; k0 < gK; k0 += 32) {
      gl_lds16(A_h + gArow + k0 + scs, ldsA);
      gl_lds16(A_m + gArow + k0 + scs, ldsAm);
      if (gnt == 3) gl_lds16(A_l + gArow + k0 + scs, ldsAl);
      gl_lds16(Wh + gBrow + k0 + scs, ldsB);
      gl_lds16(Wm + gBrow + k0 + scs, ldsBm);
      if (gnt == 3) gl_lds16(Wl + gBrow + k0 + scs, ldsBl);
      __syncthreads();
      short8 afh[4], afm[4], afl[4];
#pragma unroll
      for (int mi = 0; mi < 4; ++mi) {
        int rr = wm * 64 + mi * 16 + lm;
        int ro = rr * 32 + (((lane >> 4) ^ ((rr >> 1) & 3)) << 3);
        afh[mi] = *(const short8*)&AshL[ro];
        afm[mi] = *(const short8*)&AsmL[ro];
        if (gnt == 3) afl[mi] = *(const short8*)&AslL[ro];
      }
#pragma unroll
      for (int ni = 0; ni < 2; ++ni) {
        int rb = wn * 32 + ni * 16 + lm;
        int ro = rb * 32 + (((lane >> 4) ^ ((rb >> 1) & 3)) << 3);
        short8 bfh = *(const short8*)&BshL[ro];
        short8 bfm = *(const short8*)&BsmL[ro];
#pragma unroll
        for (int mi = 0; mi < 4; ++mi) {
          floatx4 a = acc[mi][ni];
          a = __builtin_amdgcn_mfma_f32_16x16x32_bf16(afh[mi], bfh, a, 0, 0, 0);
          a = __builtin_amdgcn_mfma_f32_16x16x32_bf16(afh[mi], bfm, a, 0, 0, 0);
          a = __builtin_amdgcn_mfma_f32_16x16x32_bf16(afm[mi], bfh, a, 0, 0, 0);
          if (gnt == 3) {
            short8 bfl = *(const short8*)&BslL[ro];
            a = __builtin_amdgcn_mfma_f32_16x16x32_bf16(afh[mi], bfl, a, 0, 0, 0);
            a = __builtin_amdgcn_mfma_f32_16x16x32_bf16(afl[mi], bfh, a, 0, 0, 0);
            a = __builtin_amdgcn_mfma_f32_16x16x32_bf16(afm[mi], bfm, a, 0, 0, 0);
          }
          acc[mi][ni] = a;
        }
      }
      __syncthreads();
    }
    int lr = (lane >> 4) * 4;
#pragma unroll
    for (int mi = 0; mi < 4; ++mi)
#pragma unroll
      for (int ni = 0; ni < 2; ++ni) {
        int colg = col0 + wn * 32 + ni * 16 + lm;
        if (colg >= gN) continue;
#pragma unroll
        for (int r = 0; r < 4; ++r) {
          int rowg = row0 + wm * 64 + mi * 16 + lr + r;
          C[(size_t)rowg * gN + colg] = acc[mi][ni][r];
        }
      }
  }
}

// ------------- fused degree head: xdeg = relu(relu(relu(X@W4+b4)@W5+b5)·w6+b6) -------------
__global__ __launch_bounds__(256) void degree_head_kernel(
    const short* __restrict__ Xh, const short* __restrict__ Xm,
    const short* __restrict__ W4h, const short* __restrict__ W4m, const float* __restrict__ b4,
    const short* __restrict__ W5h, const short* __restrict__ W5m, const float* __restrict__ b5,
    const float* __restrict__ w6, const float* __restrict__ b6,
    float* __restrict__ xdeg) {
  __shared__ __attribute__((aligned(16))) short Ash[32 * 40];
  __shared__ __attribute__((aligned(16))) short Asm[32 * 40];
  __shared__ __attribute__((aligned(16))) short Bsh[256 * 40];
  __shared__ __attribute__((aligned(16))) short Bsm[256 * 40];
  __shared__ __attribute__((aligned(16))) short H1h[32][264];
  __shared__ __attribute__((aligned(16))) short H1m[32][264];
  __shared__ float rowsum[32];
  int tid = threadIdx.x;
  int wave = tid >> 6, lane = tid & 63;
  int lm = lane & 15, g = lane >> 4, lk = g * 8;
  int row0 = blockIdx.x * 32;

  floatx4 acc[2][4] = {};
  for (int k0 = 0; k0 < 256; k0 += 32) {
    {
      int e = tid;
      int a = e >> 7, rem = e & 127;
      int r = rem >> 2, kc = (rem & 3) * 8;
      const short* src = a ? Xm : Xh;
      short* dst = a ? Asm : Ash;
      *(short8*)&dst[r * 40 + kc] = *(const short8*)&src[(size_t)(row0 + r) * 256 + k0 + kc];
    }
#pragma unroll
    for (int i = 0; i < 8; ++i) {
      int e = tid + i * 256;
      int a = e >> 10, rem = e & 1023;
      int r = rem >> 2, kc = (rem & 3) * 8;
      const short* src = a ? W4m : W4h;
      short* dst = a ? Bsm : Bsh;
      *(short8*)&dst[r * 40 + kc] = *(const short8*)&src[(size_t)r * 256 + k0 + kc];
    }
    __syncthreads();
    short8 afh[2], afm[2];
#pragma unroll
    for (int rt = 0; rt < 2; ++rt) {
      int ro = (rt * 16 + lm) * 40 + lk;
      afh[rt] = *(const short8*)&Ash[ro];
      afm[rt] = *(const short8*)&Asm[ro];
    }
#pragma unroll
    for (int ct = 0; ct < 4; ++ct) {
      int ro = (wave * 64 + ct * 16 + lm) * 40 + lk;
      short8 bfh = *(const short8*)&Bsh[ro];
      short8 bfm = *(const short8*)&Bsm[ro];
#pragma unroll
      for (int rt = 0; rt < 2; ++rt) {
        floatx4 a = acc[rt][ct];
        a = __builtin_amdgcn_mfma_f32_16x16x32_bf16(afh[rt], bfh, a, 0, 0, 0);
        a = __builtin_amdgcn_mfma_f32_16x16x32_bf16(afh[rt], bfm, a, 0, 0, 0);
        a = __builtin_amdgcn_mfma_f32_16x16x32_bf16(afm[rt], bfh, a, 0, 0, 0);
        acc[rt][ct] = a;
      }
    }
    __syncthreads();
  }
#pragma unroll
  for (int rt = 0; rt < 2; ++rt)
#pragma unroll
    for (int ct = 0; ct < 4; ++ct) {
      int col = wave * 64 + ct * 16 + lm;
      float bv = b4[col];
#pragma unroll
      for (int r = 0; r < 4; ++r) {
        int row = rt * 16 + g * 4 + r;
        float v = fmaxf(acc[rt][ct][r] + bv, 0.f);
        short hh = f2b(v);
        H1h[row][col] = hh;
        H1m[row][col] = f2b(v - b2f(hh));
      }
    }
  if (tid < 32) rowsum[tid] = 0.f;
  __syncthreads();

  floatx4 acc2[2][2] = {};
  for (int k0 = 0; k0 < 256; k0 += 32) {
#pragma unroll
    for (int i = 0; i < 4; ++i) {
      int e = tid + i * 256;
      int a = e >> 9, rem = e & 511;
      int r = rem >> 2, kc = (rem & 3) * 8;
      const short* src = a ? W5m : W5h;
      short* dst = a ? Bsm : Bsh;
      *(short8*)&dst[r * 40 + kc] = *(const short8*)&src[(size_t)r * 256 + k0 + kc];
    }
    __syncthreads();
    short8 afh[2], afm[2];
#pragma unroll
    for (int rt = 0; rt < 2; ++rt) {
      afh[rt] = *(const short8*)&H1h[rt * 16 + lm][k0 + lk];
      afm[rt] = *(const short8*)&H1m[rt * 16 + lm][k0 + lk];
    }
#pragma unroll
    for (int ct = 0; ct < 2; ++ct) {
      int ro = (wave * 32 + ct * 16 + lm) * 40 + lk;
      short8 bfh = *(const short8*)&Bsh[ro];
      short8 bfm = *(const short8*)&Bsm[ro];
#pragma unroll
      for (int rt = 0; rt < 2; ++rt) {
        floatx4 a = acc2[rt][ct];
        a = __builtin_amdgcn_mfma_f32_16x16x32_bf16(afh[rt], bfh, a, 0, 0, 0);
        a = __builtin_amdgcn_mfma_f32_16x16x32_bf16(afh[rt], bfm, a, 0, 0, 0);
        a = __builtin_amdgcn_mfma_f32_16x16x32_bf16(afm[rt], bfh, a, 0, 0, 0);
        acc2[rt][ct] = a;
      }
    }
    __syncthreads();
  }
#pragma unroll
  for (int rt = 0; rt < 2; ++rt) {
#pragma unroll
    for (int r = 0; r < 4; ++r) {
      float p = 0.f;
#pragma unroll
      for (int ct = 0; ct < 2; ++ct) {
        int col = wave * 32 + ct * 16 + lm;
        float v = fmaxf(acc2[rt][ct][r] + b5[col], 0.f);
        p += v * w6[col];
      }
#pragma unroll
      for (int off = 1; off < 16; off <<= 1) p += __shfl_xor(p, off, 64);
      if (lm == 0) atomicAdd(&rowsum[rt * 16 + g * 4 + r], p);
    }
  }
  __syncthreads();
  if (tid < 32) xdeg[row0 + tid] = fmaxf(rowsum[tid] + b6[0], 0.f);
}

// scalar edge agg (Hc not divisible by 4); AB is (rows x 2Hc)
__global__ void edge_agg_kernel(const float* __restrict__ AB, const float* __restrict__ bias,
                                const int* __restrict__ idx, int n, int Hc, int act,
                                int rows, int per,
                                float* __restrict__ out,
                                short* __restrict__ outh, short* __restrict__ outm,
                                short* __restrict__ outl) {
  int t = blockIdx.x * blockDim.x + threadIdx.x;
  if (t >= rows * Hc) return;
  int r = t / Hc, h = t - r * Hc;
  int d = r / per, rloc = r - d * per;
  int b = rloc / n;
  int s2 = 2 * Hc;
  float av = AB[(size_t)r * s2 + h] + bias[h];
  const int* ir = idx + ((size_t)d * per + rloc) * KNN_;
  int base = d * per + b * n;
  float m = -INFINITY;
  for (int k = 0; k < KNN_; ++k) {
    float v = av + AB[(size_t)(base + ir[k]) * s2 + Hc + h];
    v = fmaxf(v, 0.f);
    m = fmaxf(m, v);
  }
  if (act == 2) m = tanhf(m);
  if (out) out[t] = m;
  if (outh) {
    short hh, mm, ll;
    f2b3(m, hh, mm, ll);
    outh[t] = hh; outm[t] = mm;
    if (outl) outl[t] = ll;
  }
}

// vectorized edge agg: 4 features/thread, 8 rows/block (rows%8==0 required at call sites).
// Per-element FP order identical to scalar. Optional colsums: per-column double s/s2
// accumulated in registers over the block's 8 rows, LDS-reduced, one atomicAdd per column
// per block (replaces the uncoalesced bn_stats pass; double reassociation only).
__global__ __launch_bounds__(256) void edge_agg4_kernel(
    const float* __restrict__ AB, const float* __restrict__ bias,
    const int* __restrict__ idx, int n, int Hc, int act,
    int rows, int per,
    float* __restrict__ out,
    short* __restrict__ outh, short* __restrict__ outm, short* __restrict__ outl,
    double* __restrict__ colsums) {
  __shared__ double lds_s[4][256];
  __shared__ double lds_s2[4][256];
  int tid = threadIdx.x;
  int hq = tid & 63, rl = tid >> 6;
  int h = hq << 2;
  int s2s = 2 * Hc;
  double cs[4] = {0.0, 0.0, 0.0, 0.0}, cs2[4] = {0.0, 0.0, 0.0, 0.0};
#pragma unroll
  for (int sub = 0; sub < 2; ++sub) {
    int r = blockIdx.x * 8 + rl + sub * 4;
    if (r < rows) {
      int d = r / per, rloc = r - d * per;
      int b = rloc / n;
      float4 av = *(const float4*)&AB[(size_t)r * s2s + h];
      float4 bv = *(const float4*)&bias[h];
      float a0 = av.x + bv.x, a1 = av.y + bv.y, a2 = av.z + bv.z, a3 = av.w + bv.w;
      const int* ir = idx + ((size_t)d * per + rloc) * KNN_;
      int base = d * per + b * n;
      int nb[KNN_];
#pragma unroll
      for (int k = 0; k < KNN_; ++k) nb[k] = base + ir[k];
      float m0 = -INFINITY, m1 = -INFINITY, m2 = -INFINITY, m3 = -INFINITY;
#pragma unroll
      for (int k = 0; k < KNN_; ++k) {
        float4 bb = *(const float4*)&AB[(size_t)nb[k] * s2s + Hc + h];
        m0 = fmaxf(m0, fmaxf(a0 + bb.x, 0.f));
        m1 = fmaxf(m1, fmaxf(a1 + bb.y, 0.f));
        m2 = fmaxf(m2, fmaxf(a2 + bb.z, 0.f));
        m3 = fmaxf(m3, fmaxf(a3 + bb.w, 0.f));
      }
      if (act == 2) { m0 = tanhf(m0); m1 = tanhf(m1); m2 = tanhf(m2); m3 = tanhf(m3); }
      size_t o = (size_t)r * Hc + h;
      if (out) *(float4*)&out[o] = make_float4(m0, m1, m2, m3);
      if (outh) {
        short h0, mm0, l0, h1, mm1, l1, h2, mm2, l2, h3, mm3, l3;
        f2b3(m0, h0, mm0, l0); f2b3(m1, h1, mm1, l1);
        f2b3(m2, h2, mm2, l2); f2b3(m3, h3, mm3, l3);
        short4v vh = {h0, h1, h2, h3};
        short4v vm = {mm0, mm1, mm2, mm3};
        *(short4v*)&outh[o] = vh;
        *(short4v*)&outm[o] = vm;
        if (outl) {
          short4v vl = {l0, l1, l2, l3};
          *(short4v*)&outl[o] = vl;
        }
      }
      if (colsums) {
        double d0 = (double)m0, d1 = (double)m1, d2 = (double)m2, d3 = (double)m3;
        cs[0] += d0; cs2[0] += d0 * d0;
        cs[1] += d1; cs2[1] += d1 * d1;
        cs[2] += d2; cs2[2] += d2 * d2;
        cs[3] += d3; cs2[3] += d3 * d3;
      }
    }
  }
  if (colsums) {
#pragma unroll
    for (int j = 0; j < 4; ++j) {
      lds_s[rl][h + j] = cs[j];
      lds_s2[rl][h + j] = cs2[j];
    }
    __syncthreads();
    int c = tid;
    double ss = ((lds_s[0][c] + lds_s[1][c]) + lds_s[2][c]) + lds_s[3][c];
    double ss2 = ((lds_s2[0][c] + lds_s2[1][c]) + lds_s2[2][c]) + lds_s2[3][c];
    atomicAdd(&colsums[c], ss);
    atomicAdd(&colsums[256 + c], ss2);
  }
}

// -------- fused sag select + pool + readout (+gtpred pass-through, +classifier) ----
// 1024 threads (16 waves). scsh computed in-block from colsums (bn_stats formula).
// The graph's t1 block (n x 256 floats) and adj block (n x n floats) are staged into LDS
// once with coalesced loads; every phase (ys/dinv/gcn/adjp/pool) reads LDS afterward —
// identical values & FP order as reading global (bit-exact), but ~3x less latency-bound.
__global__ __launch_bounds__(1024) void sag_pool_kernel(
    const float* __restrict__ t1,
    const double* __restrict__ colsums, const float* __restrict__ bng,
    const float* __restrict__ bnb, int M,
    const float* __restrict__ pw,
    const float* __restrict__ adj_in, int n, int k,
    const float* __restrict__ pb,
    int* __restrict__ perm, float* __restrict__ adjp,
    const float* __restrict__ deg, const float* __restrict__ xdeg,
    float* __restrict__ gt, float* __restrict__ pred,
    const int* __restrict__ gperm, int gk, float* __restrict__ ggt, float* __restrict__ gpred,
    const int* __restrict__ remap, int accum,
    short* __restrict__ xph, short* __restrict__ xpm, short* __restrict__ xpl,
    short* __restrict__ soh, short* __restrict__ som, float* __restrict__ z,
    const float* __restrict__ W1, const float* __restrict__ b1,
    const float* __restrict__ W2, const float* __restrict__ b2,
    const float* __restrict__ W3, const float* __restrict__ b3,
    float* __restrict__ probs) {
  __shared__ float ys[40], dinv[40], scs[40], tant[40];
  __shared__ int locs[40];
  __shared__ __attribute__((aligned(16))) float t1L[39 * 256];   // graph's t1 block
  __shared__ __attribute__((aligned(16))) float adjL[39 * 39];   // graph's adj block
  __shared__ __attribute__((aligned(16))) float scshL[512];
  __shared__ __attribute__((aligned(16))) float pmx[4][256];
  __shared__ __attribute__((aligned(16))) float psm[4][256];
  __shared__ __attribute__((aligned(16))) float ca[512];
  __shared__ __attribute__((aligned(16))) float z1s[256];
  __shared__ __attribute__((aligned(16))) float z2s[128];
  __shared__ float lg[2];
  int b = blockIdx.x;
  int i = threadIdx.x;
  int wave = i >> 6, lane = i & 63;
  // ---- coalesced staging: t1 (n*256 floats) + adj (n*n floats), both contiguous ----
  {
    const float* src = t1 + (size_t)(b * n) * H_;
    int tot = n * H_;
    for (int e = i; e < tot; e += 1024) t1L[e] = src[e];
    const float* asrc = adj_in + (size_t)b * n * n;
    int atot = n * n;
    for (int e = i; e < atot; e += 1024) adjL[e] = asrc[e];
  }
  if (i < 256) {   // bn finalize (exact bn_stats formula)
    double mean = colsums[i] / M;
    double var = colsums[256 + i] / M - mean * mean;
    float rstd = 1.f / sqrtf((float)var + 1e-5f);
    float sc = rstd * bng[i];
    scshL[i] = sc;
    scshL[256 + i] = bnb[i] - (float)mean * sc;
  }
  __syncthreads();
  // ys rowdot: 16 waves, per-row FP order identical to original
  for (int row = wave; row < n; row += 16) {
    const float* xr = &t1L[row * H_];
    float s = 0.f;
    for (int kk = lane; kk < H_; kk += 64) {
      float v = fmaxf(xr[kk] * scshL[kk] + scshL[H_ + kk], 0.f);
      s += v * pw[kk];
    }
    for (int off = 32; off; off >>= 1) s += __shfl_down(s, off, 64);
    if (lane == 0) ys[row] = s;
  }
  __syncthreads();
  if (i < n) {
    const float* ar = &adjL[i * n];
    float sum = 1.f;
    for (int j = 0; j < n; ++j) sum += ar[j];
    dinv[i] = 1.f / sqrtf(sum);
  }
  __syncthreads();
  if (i < n) {
    const float* ar = &adjL[i * n];
    float acc = 0.f;
    for (int j = 0; j < n; ++j) {
      float a = ar[j] + (i == j ? 1.f : 0.f);
      acc += a * dinv[j] * ys[j];
    }
    scs[i] = dinv[i] * acc + pb[0];
  }
  __syncthreads();
  if (i < n) {   // rank-based stable descending top-k (ties -> lowest index)
    float si = scs[i];
    int rank = 0;
    for (int j = 0; j < n; ++j) {
      float sj = scs[j];
      rank += (sj > si || (sj == si && j < i)) ? 1 : 0;
    }
    if (rank < k) {
      tant[rank] = tanhf(si);
      locs[rank] = i;
      perm[b * k + rank] = b * n + i;
    }
  }
  __syncthreads();
  if (adjp) {
    for (int e = threadIdx.x; e < k * k; e += 1024) {
      int t1i = e / k, t2i = e - t1i * k;
      adjp[(size_t)b * k * k + e] = adjL[locs[t1i] * n + locs[t2i]];
    }
  }
  if (gt && threadIdx.x < k) {
    int p = b * n + locs[threadIdx.x];
    gt[b * k + threadIdx.x] = deg[p];
    pred[b * k + threadIdx.x] = xdeg[p];
  }
  if (ggt && threadIdx.x < gk) {     // previous level's gtpred (graph-local)
    int p = gperm[b * gk + threadIdx.x];
    ggt[b * gk + threadIdx.x] = deg[p];
    gpred[b * gk + threadIdx.x] = xdeg[p];
  }
  // ---- pool + readout: r-loop split across 4 groups of 256 threads ----
  int hc = i & 255;
  int rg = i >> 8;                   // 0..3
  float sc = scshL[hc], sh = scshL[H_ + hc];
  float mx = -INFINITY, sm = 0.f;
  for (int r = rg; r < k; r += 4) {
    int loc = locs[r];
    float tg = tant[r];
    float v = fmaxf(t1L[loc * H_ + hc] * sc + sh, 0.f) * tg;
    short hh, mm, ll;
    f2b3(v, hh, mm, ll);
    size_t xo = ((size_t)(b * k + r)) * H_ + hc;
    xph[xo] = hh; xpm[xo] = mm; xpl[xo] = ll;
    int own = b * n + loc;
    int tgt = remap ? remap[own] : own;
    size_t so = (size_t)tgt * H_ + hc;
    soh[so] = hh; som[so] = mm;
    float vq = b2f(hh) + b2f(mm) + b2f(ll);
    mx = fmaxf(mx, vq);
    sm += vq;
  }
  pmx[rg][hc] = mx;
  psm[rg][hc] = sm;
  __syncthreads();
  if (i < 256) {
    float m0 = fmaxf(fmaxf(pmx[0][hc], pmx[1][hc]), fmaxf(pmx[2][hc], pmx[3][hc]));
    float s0 = ((psm[0][hc] + psm[1][hc]) + psm[2][hc]) + psm[3][hc];
    float* zb = z + (size_t)b * 2 * H_;
    float mean = s0 / (float)k;
    float zr1, zr2;
    if (accum) { zr1 = zb[hc] + m0; zr2 = zb[H_ + hc] + mean; zb[hc] = zr1; zb[H_ + hc] = zr2; }
    else       { zr1 = m0;  zr2 = mean; zb[hc] = zr1; zb[H_ + hc] = zr2; }
    if (probs) { ca[hc] = zr1; ca[H_ + hc] = zr2; }
  }
  // ---- classifier phase (final level only): identical values/order to before ----
  if (probs) {
    __syncthreads();
    if (i < 256) {  // layer 1: N=256, K=512, relu
      int c = hc;
      float s = 0.f;
      for (int kk = 0; kk < 512; kk += 4) {
        float4 av = *(const float4*)&ca[kk];
        s += av.x * W1[(size_t)kk * 256 + c];
        s += av.y * W1[(size_t)(kk + 1) * 256 + c];
        s += av.z * W1[(size_t)(kk + 2) * 256 + c];
        s += av.w * W1[(size_t)(kk + 3) * 256 + c];
      }
      z1s[c] = fmaxf(s + b1[c], 0.f);
    }
    __syncthreads();
    if (i < 128) {  // layer 2: N=128, K=256, relu
      int c = i;
      float s = 0.f;
      for (int kk = 0; kk < 256; kk += 4) {
        float4 av = *(const float4*)&z1s[kk];
        s += av.x * W2[(size_t)kk * 128 + c];
        s += av.y * W2[(size_t)(kk + 1) * 128 + c];
        s += av.z * W2[(size_t)(kk + 2) * 128 + c];
        s += av.w * W2[(size_t)(kk + 3) * 128 + c];
      }
      z2s[c] = fmaxf(s + b2[c], 0.f);
    }
    __syncthreads();
    if (wave < 2) {   // layer 3: N=2, K=128 (wavedot order)
      float s = 0.f;
      for (int kk = lane; kk < 128; kk += 64) s += z2s[kk] * W3[(size_t)kk * 2 + wave];
      for (int off = 32; off; off >>= 1) s += __shfl_down(s, off, 64);
      if (lane == 0) lg[wave] = s + b3[wave];
    }
    __syncthreads();
    if (i == 0) {
      float aa = lg[0], cc = lg[1];
      float m = fmaxf(aa, cc);
      float ea = expf(aa - m), ec = expf(cc - m);
      float inv = 1.f / (ea + ec);
      probs[2 * b] = ea * inv;
      probs[2 * b + 1] = ec * inv;
    }
  }
}

extern "C" void kernel_launch(void* const* d_in, const int* in_sizes, int n_in,
                              void* d_out, int out_size, void* d_ws, size_t ws_size,
                              hipStream_t stream) {
  auto in = [&](int i) { return (const float*)d_in[i]; };
  const float* x      = in(0);
  const float* adj    = in(1);
  const float* w_mlp1 = in(2);  const float* b_mlp1 = in(3);
  const float* w_mlp2 = in(4);  const float* b_mlp2 = in(5);
  const float* w_mlp3 = in(6);  const float* b_mlp3 = in(7);
  const float* w_mlp6 = in(8);  const float* b_mlp6 = in(9);
  const float* bn1_g = in(10);  const float* bn1_b = in(11);
  const float* bn2_g = in(12);  const float* bn2_b = in(13);
  const float* bn3_g = in(14);  const float* bn3_b = in(15);
  const float* p1_w = in(16);   const float* p1_b = in(17);
  const float* p2_w = in(18);   const float* p2_b = in(19);
  const float* p3_w = in(20);   const float* p3_b = in(21);
  const float* lin1_w = in(22); const float* lin1_b = in(23);
  const float* lin2_w = in(24); const float* lin2_b = in(25);
  const float* lin3_w = in(26); const float* lin3_b = in(27);
  const float* lin4_w = in(28); const float* lin4_b = in(29);
  const float* lin5_w = in(30); const float* lin5_b = in(31);
  const float* lin6_w = in(32); const float* lin6_b = in(33);

  float* out = (float*)d_out;
  float* out_probs = out;
  float* out_dec1  = out_probs + 256;            // 3 x 4992*39 contiguous
  float* out_gt1   = out_dec1 + 3 * 4992 * 39;
  float* out_pred1 = out_gt1 + 4096;
  float* out_gt2   = out_pred1 + 4096;
  float* out_pred2 = out_gt2 + 3328;
  float* out_gt3   = out_pred2 + 3328;
  float* out_pred3 = out_gt3 + 2688;

  char* base = (char*)d_ws;
  size_t off = 0;
  auto allocf = [&](size_t n) -> float* {
    float* p = (float*)(base + off);
    off += ((n * sizeof(float) + 255) & ~(size_t)255);
    return p;
  };
  auto alloci = [&](size_t n) -> int* {
    int* p = (int*)(base + off);
    off += ((n * sizeof(int) + 255) & ~(size_t)255);
    return p;
  };
  auto allocs = [&](size_t n) -> short* {
    short* p = (short*)(base + off);
    off += ((n * sizeof(short) + 255) & ~(size_t)255);
    return p;
  };
  auto allocd = [&](size_t n) -> double* {
    double* p = (double*)(base + off);
    off += ((n * sizeof(double) + 255) & ~(size_t)255);
    return p;
  };

  const size_t S = (size_t)4992 * 256;
  const size_t AB_S = (size_t)4992 * 512;
  const int SI = 4992 * KNN_;

  short* wt1h = allocs(512 * 64); short* wt1m = allocs(512 * 64); short* wt1l = allocs(512 * 64);
  short* wt2h = allocs(512 * 256); short* wt2m = allocs(512 * 256); short* wt2l = allocs(512 * 256);
  short* wt3h = allocs(512 * 256); short* wt3m = allocs(512 * 256); short* wt3l = allocs(512 * 256);
  short* wt6h = allocs(78 * 256);  short* wt6m = allocs(78 * 256);
  short* l4h = allocs(256 * 256);  short* l4m = allocs(256 * 256);
  short* l5h = allocs(128 * 256);  short* l5m = allocs(128 * 256);
  short* xsph = allocs(4992 * 64); short* xspm = allocs(4992 * 64); short* xspl = allocs(4992 * 64);
  float* deg  = allocf(4992);
  float* xdeg = allocf(4992);
  int* idxb = alloci(3 * SI);
  float* AB3 = allocf(3 * AB_S);
  float* trunk_t1 = allocf(S);
  double* bnsum = allocd(3 * 512);
  short* xph = allocs((size_t)4096 * 256); short* xpm = allocs((size_t)4096 * 256); short* xpl = allocs((size_t)4096 * 256);
  short* xoutb_h = allocs(3 * S);
  short* xoutb_m = allocs(3 * S);
  short* t1b_h = allocs(3 * S);
  short* t1b_m = allocs(3 * S);
  float* adj1 = allocf(128 * 32 * 32);
  float* adj2 = allocf(128 * 26 * 26);
  int* perm1 = alloci(4096); int* perm2 = alloci(3328); int* perm3 = alloci(2688);
  float* z  = allocf(128 * 512);
  if (off > ws_size) return;

  // t2b aliases xoutb (dead after decoder stage 1)
  short* t2b_h = xoutb_h; short* t2b_m = xoutb_m;

  const size_t LDS3 = 6 * 128 * 32 * sizeof(short);          // 49152: 3-term gemm (>= knn 21.2KB)
  const size_t LDS2 = 4 * 128 * 32 * sizeof(short);          // 32768: 2-term gemm (>= knn 17.3KB)

  // ---- prep (incl. xoutb zeroing task 8 + bnsum zeroing task 9) ----
  prep_kernel<<<6627, 256, 0, stream>>>(
      w_mlp1, w_mlp2, w_mlp3, w_mlp6, lin4_w, lin5_w, x, adj,
      wt1h, wt1m, wt1l, wt2h, wt2m, wt2l, wt3h, wt3m, wt3l, wt6h, wt6m,
      l4h, l4m, l5h, l5m, xsph, xspm, xspl, deg, xoutb_h, bnsum);

  // ---- level 1: fused knn+gemm, then agg(+bn sums)/sag+pool ----
  knn_gemm_kernel<<<B_ + 4 * 39, 512, LDS3, stream>>>(
      xsph, xspm, xspl, 3, 64, N_, 64, idxb, B_,
      xsph, xspm, xspl, 3, 64, wt1h, wt1m, wt1l, AB3, 4992, 512, 39, 0, 0);
  edge_agg4_kernel<<<4992 / 8, 256, 0, stream>>>(AB3, b_mlp1, idxb, N_, 256, 0, 4992, 4992,
                                                 trunk_t1, nullptr, nullptr, nullptr, bnsum);
  sag_pool_kernel<<<B_, 1024, 0, stream>>>(
      trunk_t1, bnsum, bn1_g, bn1_b, 4992, p1_w, adj, N_, K1_, p1_b,
      perm1, adj1, nullptr, nullptr, nullptr, nullptr,
      nullptr, 0, nullptr, nullptr,
      nullptr, 0, xph, xpm, xpl, xoutb_h, xoutb_m, z,
      nullptr, nullptr, nullptr, nullptr, nullptr, nullptr, nullptr);
  // ---- degree head from x_out1 ----
  degree_head_kernel<<<156, 256, 0, stream>>>(
      xoutb_h, xoutb_m, l4h, l4m, lin4_b, l5h, l5m, lin5_b, lin6_w, lin6_b, xdeg);

  // ---- level 2 (also emits level-1 gt/pred via graph-local gather) ----
  knn_gemm_kernel<<<B_ + 4 * 32, 512, LDS3, stream>>>(
      xph, xpm, xpl, 3, 256, K1_, 256, idxb, B_,
      xph, xpm, xpl, 3, 256, wt2h, wt2m, wt2l, AB3, 4096, 512, 32, 0, 0);
  edge_agg4_kernel<<<4096 / 8, 256, 0, stream>>>(AB3, b_mlp2, idxb, K1_, 256, 0, 4096, 4096,
                                                 trunk_t1, nullptr, nullptr, nullptr, bnsum + 512);
  sag_pool_kernel<<<B_, 1024, 0, stream>>>(
      trunk_t1, bnsum + 512, bn2_g, bn2_b, 4096, p2_w, adj1, K1_, K2_, p2_b,
      perm2, adj2, deg, xdeg, out_gt2, out_pred2,
      perm1, K1_, out_gt1, out_pred1,
      perm1, 1, xph, xpm, xpl, xoutb_h + S, xoutb_m + S, z,
      nullptr, nullptr, nullptr, nullptr, nullptr, nullptr, nullptr);

  // ---- level 3 (+ fused classifier on final z) ----
  knn_gemm_kernel<<<B_ + 4 * 26, 512, LDS3, stream>>>(
      xph, xpm, xpl, 3, 256, K2_, 256, idxb, B_,
      xph, xpm, xpl, 3, 256, wt3h, wt3m, wt3l, AB3, 3328, 512, 26, 0, 0);
  edge_agg4_kernel<<<3328 / 8, 256, 0, stream>>>(AB3, b_mlp3, idxb, K2_, 256, 0, 3328, 3328,
                                                 trunk_t1, nullptr, nullptr, nullptr, bnsum + 1024);
  sag_pool_kernel<<<B_, 1024, 0, stream>>>(
      trunk_t1, bnsum + 1024, bn3_g, bn3_b, 3328, p3_w, adj2, K2_, K3_, p3_b,
      perm3, nullptr, deg, xdeg, out_gt3, out_pred3,
      nullptr, 0, nullptr, nullptr,
      perm2, 1, xph, xpm, xpl, xoutb_h + 2 * S, xoutb_m + 2 * S, z,
      lin1_w, lin1_b, lin2_w, lin2_b, lin3_w, lin3_b, out_probs);

  // ---- batched decoders (3 independent; fused knn+gemm per stage) ----
  // stage 1: wcat3, tanh
  knn_gemm_kernel<<<3 * B_ + 4 * 39 * 3, 512, LDS2, stream>>>(
      xoutb_h, xoutb_m, nullptr, 2, 256, N_, 256, idxb, 3 * B_,
      xoutb_h, xoutb_m, nullptr, 2, 256, wt3h, wt3m, nullptr, AB3, 4992, 512, 39, S, AB_S);
  edge_agg4_kernel<<<3 * 4992 / 8, 256, 0, stream>>>(
      AB3, b_mlp3, idxb, N_, 256, 2, 3 * 4992, 4992, nullptr, t1b_h, t1b_m, nullptr, nullptr);
  // stage 2: wcat2, tanh
  knn_gemm_kernel<<<3 * B_ + 4 * 39 * 3, 512, LDS2, stream>>>(
      t1b_h, t1b_m, nullptr, 2, 256, N_, 256, idxb, 3 * B_,
      t1b_h, t1b_m, nullptr, 2, 256, wt2h, wt2m, nullptr, AB3, 4992, 512, 39, S, AB_S);
  edge_agg4_kernel<<<3 * 4992 / 8, 256, 0, stream>>>(
      AB3, b_mlp2, idxb, N_, 256, 2, 3 * 4992, 4992, nullptr, t2b_h, t2b_m, nullptr, nullptr);
  // stage 3: wcat6, linear -> out_dec (Hc=39 not divisible by 4 -> scalar)
  knn_gemm_kernel<<<3 * B_ + 1 * 39 * 3, 512, LDS2, stream>>>(
      t2b_h, t2b_m, nullptr, 2, 256, N_, 256, idxb, 3 * B_,
      t2b_h, t2b_m, nullptr, 2, 256, wt6h, wt6m, nullptr, AB3, 4992, 78, 39, S, (size_t)4992 * 78);
  edge_agg_kernel<<<cdiv(3 * 4992 * 39, 256), 256, 0, stream>>>(
      AB3, b_mlp6, idxb, N_, 39, 0, 3 * 4992, 4992, out_dec1, nullptr, nullptr, nullptr);
}

// Round 19
// 427.505 us; speedup vs baseline: 1.0173x; 1.0028x over previous
//
#include <hip/hip_runtime.h>
#include <hip/hip_cooperative_groups.h>
#include <cmath>

namespace cg = cooperative_groups;

#define B_   128
#define N_   39
#define KNN_ 10
#define H_   256
#define K1_  32
#define K2_  26
#define K3_  21

static inline int cdiv(int a, int b) { return (a + b - 1) / b; }

typedef __attribute__((ext_vector_type(8))) short short8;
typedef __attribute__((ext_vector_type(4))) short short4v;
typedef __attribute__((ext_vector_type(4))) float floatx4;

__device__ inline short f2b(float f) {   // fp32 -> bf16 RNE
  unsigned u = __float_as_uint(f);
  u += 0x7fff + ((u >> 16) & 1);
  return (short)(u >> 16);
}
__device__ inline float b2f(short h) {
  return __uint_as_float(((unsigned)(unsigned short)h) << 16);
}
__device__ inline void f2b3(float v, short& h, short& m, short& l) {  // v ~= h+m+l (24 bits)
  h = f2b(v);
  float r1 = v - b2f(h);
  m = f2b(r1);
  l = f2b(r1 - b2f(m));
}

// async global->LDS 16B (dest is wave-uniform base + lane*16: pass lane-linear ptr)
__device__ __forceinline__ void gl_lds16(const short* g, short* l) {
  __builtin_amdgcn_global_load_lds(
      (const __attribute__((address_space(1))) unsigned int*)g,
      (__attribute__((address_space(3))) unsigned int*)l, 16, 0, 0);
}

// ------------- one-shot prep (flattened 1-D grid, exact per-task block ranges) -------------
// task 8: zero xoutb scatter targets; task 9: zero bn column-sum accumulators.
__global__ void prep_kernel(
    const float* __restrict__ w1, const float* __restrict__ w2,
    const float* __restrict__ w3, const float* __restrict__ w6,
    const float* __restrict__ l4, const float* __restrict__ l5,
    const float* __restrict__ x, const float* __restrict__ adj,
    short* __restrict__ wt1h, short* __restrict__ wt1m, short* __restrict__ wt1l,
    short* __restrict__ wt2h, short* __restrict__ wt2m, short* __restrict__ wt2l,
    short* __restrict__ wt3h, short* __restrict__ wt3m, short* __restrict__ wt3l,
    short* __restrict__ wt6h, short* __restrict__ wt6m,
    short* __restrict__ l4h, short* __restrict__ l4m,
    short* __restrict__ l5h, short* __restrict__ l5m,
    short* __restrict__ xsph, short* __restrict__ xspm, short* __restrict__ xspl,
    float* __restrict__ deg, short* __restrict__ zbase, double* __restrict__ bnsum) {
  int blk = blockIdx.x;
  int task, base;
  if      (blk < 128)  { task = 0; base = 0; }
  else if (blk < 640)  { task = 1; base = 128; }
  else if (blk < 1152) { task = 2; base = 640; }
  else if (blk < 1230) { task = 3; base = 1152; }
  else if (blk < 1486) { task = 4; base = 1230; }
  else if (blk < 1614) { task = 5; base = 1486; }
  else if (blk < 2862) { task = 6; base = 1614; }
  else if (blk < 2882) { task = 7; base = 2862; }
  else if (blk < 6626) { task = 8; base = 2882; }
  else                 { task = 9; base = 6626; }
  int t = (blk - base) * 256 + threadIdx.x;
  if (task == 0) {            // wcat1 tripleT: [512][64], K=39 padded
    if (t >= 512 * 64) return;
    int nn = t >> 6, k = t & 63;
    float v = 0.f;
    if (k < 39) v = (nn < 256) ? w1[k * 256 + nn] - w1[(39 + k) * 256 + nn]
                               : w1[(39 + k) * 256 + (nn - 256)];
    short h, m, l; f2b3(v, h, m, l);
    wt1h[t] = h; wt1m[t] = m; wt1l[t] = l;
  } else if (task == 1) {     // wcat2 tripleT: [512][256]
    if (t >= 512 * 256) return;
    int nn = t >> 8, k = t & 255;
    float v = (nn < 256) ? w2[k * 256 + nn] - w2[(256 + k) * 256 + nn]
                         : w2[(256 + k) * 256 + (nn - 256)];
    short h, m, l; f2b3(v, h, m, l);
    wt2h[t] = h; wt2m[t] = m; wt2l[t] = l;
  } else if (task == 2) {     // wcat3 tripleT
    if (t >= 512 * 256) return;
    int nn = t >> 8, k = t & 255;
    float v = (nn < 256) ? w3[k * 256 + nn] - w3[(256 + k) * 256 + nn]
                         : w3[(256 + k) * 256 + (nn - 256)];
    short h, m, l; f2b3(v, h, m, l);
    wt3h[t] = h; wt3m[t] = m; wt3l[t] = l;
  } else if (task == 3) {     // wcat6 T (h,m): [78][256]
    if (t >= 78 * 256) return;
    int nn = t >> 8, k = t & 255;
    float v = (nn < 39) ? w6[k * 39 + nn] - w6[(256 + k) * 39 + nn]
                        : w6[(256 + k) * 39 + (nn - 39)];
    short h, m, l; f2b3(v, h, m, l);
    wt6h[t] = h; wt6m[t] = m;
  } else if (task == 4) {     // lin4 T (h,m): [256][256]
    if (t >= 256 * 256) return;
    int nn = t >> 8, k = t & 255;
    short h, m, l; f2b3(l4[k * 256 + nn], h, m, l);
    l4h[t] = h; l4m[t] = m;
  } else if (task == 5) {     // lin5 T (h,m): [128][256]
    if (t >= 128 * 256) return;
    int nn = t >> 8, k = t & 255;
    short h, m, l; f2b3(l5[k * 128 + nn], h, m, l);
    l5h[t] = h; l5m[t] = m;
  } else if (task == 6) {     // x split: [4992][64], F=39 padded
    if (t >= 4992 * 64) return;
    int r = t >> 6, k = t & 63;
    float v = (k < 39) ? x[r * 39 + k] : 0.f;
    short h, m, l; f2b3(v, h, m, l);
    xsph[t] = h; xspm[t] = m; xspl[t] = l;
  } else if (task == 7) {     // degree
    if (t >= B_ * N_) return;
    const float* row = adj + (size_t)t * N_;
    float s = 0.f;
    for (int j = 0; j < N_; ++j) s += row[j];
    deg[t] = s;
  } else if (task == 8) {     // zero xoutb (958464 x 16B chunks)
    if (t >= 958464) return;
    short8 zz = {};
    *(short8*)&zbase[(size_t)t * 8] = zz;
  } else {                    // zero bn sums: 3 levels x 512 doubles
    if (t >= 256) return;
    for (int j = 0; j < 6; ++j) bnsum[t + j * 256] = 0.0;
  }
}

// ======== fused KNN + GEMM (levels + decoder fallback path) ========
__global__ __launch_bounds__(512) void knn_gemm_kernel(
    const short* __restrict__ kxh, const short* __restrict__ kxm, const short* __restrict__ kxl,
    int knt, int kKs, int kn, int kF32, int* __restrict__ idx, int knnB,
    const short* __restrict__ Ah, const short* __restrict__ Am, const short* __restrict__ Al,
    int gnt, int gK,
    const short* __restrict__ Wh, const short* __restrict__ Wm, const short* __restrict__ Wl,
    float* __restrict__ C0, int gM, int gN, int gyB,
    size_t Astride, size_t Cstride) {
  extern __shared__ char smem[];
  int tid = threadIdx.x;
  int wave = tid >> 6, lane = tid & 63;
  int lm = lane & 15, lk = (lane >> 4) * 8;
  if ((int)blockIdx.x < knnB) {
    short* sh_h = (short*)smem;
    short* sh_m = sh_h + 48 * 40;
    short* sh_l = sh_m + 48 * 40;
    float* Gs   = (float*)(sh_l + 48 * 40);    // [48][49]
    float* diag = Gs + 48 * 49;
    int b = blockIdx.x;
    int nt = (kn + 15) >> 4;
    int tasks = nt * nt;
    floatx4 acc[2] = {};
    int stage_elems = 384 * knt;
    for (int k0 = 0; k0 < kF32; k0 += 32) {
      for (int e = tid; e < stage_elems; e += 512) {
        int a = e / 384, rem = e - a * 384;
        int r = rem >> 3, c4 = (rem & 7) * 4;
        const short* src = (a == 0) ? kxh : (a == 1) ? kxm : kxl;
        short* dst = (a == 0) ? sh_h : (a == 1) ? sh_m : sh_l;
        *(short4v*)&dst[r * 40 + c4] =
            *(const short4v*)&src[((size_t)(b * kn + r)) * kKs + k0 + c4];
      }
      __syncthreads();
#pragma unroll
      for (int ai = 0; ai < 2; ++ai) {
        int t = wave + ai * 8;
        if (t < tasks) {
          int ti = t / nt, tj = t - ti * nt;
          int ra = (ti * 16 + lm) * 40 + lk;
          int rb = (tj * 16 + lm) * 40 + lk;
          short8 ah = *(const short8*)&sh_h[ra];
          short8 am = *(const short8*)&sh_m[ra];
          short8 bh = *(const short8*)&sh_h[rb];
          short8 bm = *(const short8*)&sh_m[rb];
          floatx4 a = acc[ai];
          a = __builtin_amdgcn_mfma_f32_16x16x32_bf16(ah, bh, a, 0, 0, 0);
          a = __builtin_amdgcn_mfma_f32_16x16x32_bf16(ah, bm, a, 0, 0, 0);
          a = __builtin_amdgcn_mfma_f32_16x16x32_bf16(am, bh, a, 0, 0, 0);
          if (knt == 3) {
            short8 al = *(const short8*)&sh_l[ra];
            short8 bl = *(const short8*)&sh_l[rb];
            a = __builtin_amdgcn_mfma_f32_16x16x32_bf16(ah, bl, a, 0, 0, 0);
            a = __builtin_amdgcn_mfma_f32_16x16x32_bf16(al, bh, a, 0, 0, 0);
            a = __builtin_amdgcn_mfma_f32_16x16x32_bf16(am, bm, a, 0, 0, 0);
          }
          acc[ai] = a;
        }
      }
      __syncthreads();
    }
#pragma unroll
    for (int ai = 0; ai < 2; ++ai) {
      int t = wave + ai * 8;
      if (t < tasks) {
        int ti = t / nt, tj = t - ti * nt;
        int col = tj * 16 + lm;
        int rbase = ti * 16 + (lane >> 4) * 4;
#pragma unroll
        for (int r = 0; r < 4; ++r) Gs[(rbase + r) * 49 + col] = acc[ai][r];
      }
    }
    __syncthreads();
    if (tid < 48) diag[tid] = (tid < kn) ? Gs[tid * 49 + tid] : INFINITY;
    __syncthreads();
    for (int row = wave; row < kn; row += 8) {
      float gii = diag[row];
      float dj = (lane < kn) ? (gii + diag[lane] - 2.f * Gs[row * 49 + lane]) : INFINITY;
      int rank = 0;
      for (int j = 0; j < kn; ++j) {
        float djp = gii + diag[j] - 2.f * Gs[row * 49 + j];
        rank += (djp < dj || (djp == dj && j < lane)) ? 1 : 0;
      }
      if (lane < kn && rank < KNN_)
        idx[(size_t)(b * kn + row) * KNN_ + rank] = lane;
    }
  } else {
    short* AshL = (short*)smem;                 // [128][32] per term (8192 B each)
    short* AsmL = AshL + 4096;
    short* AslL = AsmL + 4096;
    short* BshL = (short*)smem + gnt * 4096;
    short* BsmL = BshL + 4096;
    short* BslL = BsmL + 4096;
    int gb = blockIdx.x - knnB;
    int gxB = (gN + 127) >> 7;
    int nb = (int)gridDim.x - knnB;
    int xcd = gb & 7, j = gb >> 3;
    int q8 = nb >> 3, r8 = nb & 7;
    int work = (xcd < r8 ? xcd * (q8 + 1) : r8 * (q8 + 1) + (xcd - r8) * q8) + j;
    int gx = work % gxB;
    int rest = work / gxB;
    int gy = rest % gyB;
    int gz = rest / gyB;
    const short* A_h = Ah + (size_t)gz * Astride;
    const short* A_m = Am ? Am + (size_t)gz * Astride : nullptr;
    const short* A_l = Al ? Al + (size_t)gz * Astride : nullptr;
    float* C = C0 + (size_t)gz * Cstride;
    int row0 = gy * 128, col0 = gx * 128;
    int wm = wave & 1, wn = wave >> 1;
    int srow = tid >> 2;
    int scs = ((tid & 3) ^ ((srow >> 1) & 3)) << 3;
    size_t gArow = (size_t)(row0 + srow) * gK;
    size_t gBrow = (size_t)(col0 + srow) * gK;
    short* ldsA = AshL + tid * 8;
    short* ldsAm = AsmL + tid * 8;
    short* ldsAl = AslL + tid * 8;
    short* ldsB = BshL + tid * 8;
    short* ldsBm = BsmL + tid * 8;
    short* ldsBl = BslL + tid * 8;
    floatx4 acc[4][2] = {};
    for (int k0 = 0; k0 < gK; k0 += 32) {
      gl_lds16(A_h + gArow + k0 + scs, ldsA);
      gl_lds16(A_m + gArow + k0 + scs, ldsAm);
      if (gnt == 3) gl_lds16(A_l + gArow + k0 + scs, ldsAl);
      gl_lds16(Wh + gBrow + k0 + scs, ldsB);
      gl_lds16(Wm + gBrow + k0 + scs, ldsBm);
      if (gnt == 3) gl_lds16(Wl + gBrow + k0 + scs, ldsBl);
      __syncthreads();
      short8 afh[4], afm[4], afl[4];
#pragma unroll
      for (int mi = 0; mi < 4; ++mi) {
        int rr = wm * 64 + mi * 16 + lm;
        int ro = rr * 32 + (((lane >> 4) ^ ((rr >> 1) & 3)) << 3);
        afh[mi] = *(const short8*)&AshL[ro];
        afm[mi] = *(const short8*)&AsmL[ro];
        if (gnt == 3) afl[mi] = *(const short8*)&AslL[ro];
      }
#pragma unroll
      for (int ni = 0; ni < 2; ++ni) {
        int rb = wn * 32 + ni * 16 + lm;
        int ro = rb * 32 + (((lane >> 4) ^ ((rb >> 1) & 3)) << 3);
        short8 bfh = *(const short8*)&BshL[ro];
        short8 bfm = *(const short8*)&BsmL[ro];
#pragma unroll
        for (int mi = 0; mi < 4; ++mi) {
          floatx4 a = acc[mi][ni];
          a = __builtin_amdgcn_mfma_f32_16x16x32_bf16(afh[mi], bfh, a, 0, 0, 0);
          a = __builtin_amdgcn_mfma_f32_16x16x32_bf16(afh[mi], bfm, a, 0, 0, 0);
          a = __builtin_amdgcn_mfma_f32_16x16x32_bf16(afm[mi], bfh, a, 0, 0, 0);
          if (gnt == 3) {
            short8 bfl = *(const short8*)&BslL[ro];
            a = __builtin_amdgcn_mfma_f32_16x16x32_bf16(afh[mi], bfl, a, 0, 0, 0);
            a = __builtin_amdgcn_mfma_f32_16x16x32_bf16(afl[mi], bfh, a, 0, 0, 0);
            a = __builtin_amdgcn_mfma_f32_16x16x32_bf16(afm[mi], bfm, a, 0, 0, 0);
          }
          acc[mi][ni] = a;
        }
      }
      __syncthreads();
    }
    int lr = (lane >> 4) * 4;
#pragma unroll
    for (int mi = 0; mi < 4; ++mi)
#pragma unroll
      for (int ni = 0; ni < 2; ++ni) {
        int colg = col0 + wn * 32 + ni * 16 + lm;
        if (colg >= gN) continue;
#pragma unroll
        for (int r = 0; r < 4; ++r) {
          int rowg = row0 + wm * 64 + mi * 16 + lr + r;
          C[(size_t)rowg * gN + colg] = acc[mi][ni][r];
        }
      }
  }
}

// ======== decoder device blocks (2-term), used by the cooperative kernel ========
__device__ __forceinline__ void dec_knn_block(char* smem, int b,
    const short* __restrict__ kxh, const short* __restrict__ kxm, int* __restrict__ idx) {
  int tid = threadIdx.x;
  int wave = tid >> 6, lane = tid & 63;
  int lm = lane & 15, lk = (lane >> 4) * 8;
  short* sh_h = (short*)smem;
  short* sh_m = sh_h + 48 * 40;
  short* sh_l = sh_m + 48 * 40;
  float* Gs   = (float*)(sh_l + 48 * 40);    // [48][49]
  float* diag = Gs + 48 * 49;
  const int kn = 39, kKs = 256, kF32 = 256, nt = 3, tasks = 9;
  floatx4 acc[2] = {};
  for (int k0 = 0; k0 < kF32; k0 += 32) {
    for (int e = tid; e < 768; e += 512) {
      int a = e / 384, rem = e - a * 384;
      int r = rem >> 3, c4 = (rem & 7) * 4;
      const short* src = (a == 0) ? kxh : kxm;
      short* dst = (a == 0) ? sh_h : sh_m;
      *(short4v*)&dst[r * 40 + c4] =
          *(const short4v*)&src[((size_t)(b * kn + r)) * kKs + k0 + c4];
    }
    __syncthreads();
#pragma unroll
    for (int ai = 0; ai < 2; ++ai) {
      int t = wave + ai * 8;
      if (t < tasks) {
        int ti = t / nt, tj = t - ti * nt;
        int ra = (ti * 16 + lm) * 40 + lk;
        int rb = (tj * 16 + lm) * 40 + lk;
        short8 ah = *(const short8*)&sh_h[ra];
        short8 am = *(const short8*)&sh_m[ra];
        short8 bh = *(const short8*)&sh_h[rb];
        short8 bm = *(const short8*)&sh_m[rb];
        floatx4 a = acc[ai];
        a = __builtin_amdgcn_mfma_f32_16x16x32_bf16(ah, bh, a, 0, 0, 0);
        a = __builtin_amdgcn_mfma_f32_16x16x32_bf16(ah, bm, a, 0, 0, 0);
        a = __builtin_amdgcn_mfma_f32_16x16x32_bf16(am, bh, a, 0, 0, 0);
        acc[ai] = a;
      }
    }
    __syncthreads();
  }
#pragma unroll
  for (int ai = 0; ai < 2; ++ai) {
    int t = wave + ai * 8;
    if (t < tasks) {
      int ti = t / nt, tj = t - ti * nt;
      int col = tj * 16 + lm;
      int rbase = ti * 16 + (lane >> 4) * 4;
#pragma unroll
      for (int r = 0; r < 4; ++r) Gs[(rbase + r) * 49 + col] = acc[ai][r];
    }
  }
  __syncthreads();
  if (tid < 48) diag[tid] = (tid < kn) ? Gs[tid * 49 + tid] : INFINITY;
  __syncthreads();
  for (int row = wave; row < kn; row += 8) {
    float gii = diag[row];
    float dj = (lane < kn) ? (gii + diag[lane] - 2.f * Gs[row * 49 + lane]) : INFINITY;
    int rank = 0;
    for (int j = 0; j < kn; ++j) {
      float djp = gii + diag[j] - 2.f * Gs[row * 49 + j];
      rank += (djp < dj || (djp == dj && j < lane)) ? 1 : 0;
    }
    if (lane < kn && rank < KNN_)
      idx[(size_t)(b * kn + row) * KNN_ + rank] = lane;
  }
  __syncthreads();   // safe reuse of smem by the block's next role
}

__device__ __forceinline__ void dec_gemm_block(char* smem, int gb, int nb,
    const short* __restrict__ Ah, const short* __restrict__ Am,
    const short* __restrict__ Wh, const short* __restrict__ Wm,
    float* __restrict__ C0, int gN, size_t Astride, size_t Cstride) {
  int tid = threadIdx.x;
  int wave = tid >> 6, lane = tid & 63;
  int lm = lane & 15;
  short* AshL = (short*)smem;
  short* AsmL = AshL + 4096;
  short* BshL = AsmL + 4096;
  short* BsmL = BshL + 4096;
  const int gK = 256, gyB = 39;
  int gxB = (gN + 127) >> 7;
  int xcd = gb & 7, j = gb >> 3;
  int q8 = nb >> 3, r8 = nb & 7;
  int work = (xcd < r8 ? xcd * (q8 + 1) : r8 * (q8 + 1) + (xcd - r8) * q8) + j;
  int gx = work % gxB;
  int rest = work / gxB;
  int gy = rest % gyB;
  int gz = rest / gyB;
  const short* A_h = Ah + (size_t)gz * Astride;
  const short* A_m = Am + (size_t)gz * Astride;
  float* C = C0 + (size_t)gz * Cstride;
  int row0 = gy * 128, col0 = gx * 128;
  int wm = wave & 1, wn = wave >> 1;
  int srow = tid >> 2;
  int scs = ((tid & 3) ^ ((srow >> 1) & 3)) << 3;
  size_t gArow = (size_t)(row0 + srow) * gK;
  size_t gBrow = (size_t)(col0 + srow) * gK;
  short* ldsA = AshL + tid * 8;
  short* ldsAm = AsmL + tid * 8;
  short* ldsB = BshL + tid * 8;
  short* ldsBm = BsmL + tid * 8;
  floatx4 acc[4][2] = {};
  for (int k0 = 0; k0 < gK; k0 += 32) {
    gl_lds16(A_h + gArow + k0 + scs, ldsA);
    gl_lds16(A_m + gArow + k0 + scs, ldsAm);
    gl_lds16(Wh + gBrow + k0 + scs, ldsB);
    gl_lds16(Wm + gBrow + k0 + scs, ldsBm);
    __syncthreads();
    short8 afh[4], afm[4];
#pragma unroll
    for (int mi = 0; mi < 4; ++mi) {
      int rr = wm * 64 + mi * 16 + lm;
      int ro = rr * 32 + (((lane >> 4) ^ ((rr >> 1) & 3)) << 3);
      afh[mi] = *(const short8*)&AshL[ro];
      afm[mi] = *(const short8*)&AsmL[ro];
    }
#pragma unroll
    for (int ni = 0; ni < 2; ++ni) {
      int rb = wn * 32 + ni * 16 + lm;
      int ro = rb * 32 + (((lane >> 4) ^ ((rb >> 1) & 3)) << 3);
      short8 bfh = *(const short8*)&BshL[ro];
      short8 bfm = *(const short8*)&BsmL[ro];
#pragma unroll
      for (int mi = 0; mi < 4; ++mi) {
        floatx4 a = acc[mi][ni];
        a = __builtin_amdgcn_mfma_f32_16x16x32_bf16(afh[mi], bfh, a, 0, 0, 0);
        a = __builtin_amdgcn_mfma_f32_16x16x32_bf16(afh[mi], bfm, a, 0, 0, 0);
        a = __builtin_amdgcn_mfma_f32_16x16x32_bf16(afm[mi], bfh, a, 0, 0, 0);
        acc[mi][ni] = a;
      }
    }
    __syncthreads();
  }
  int lr = (lane >> 4) * 4;
#pragma unroll
  for (int mi = 0; mi < 4; ++mi)
#pragma unroll
    for (int ni = 0; ni < 2; ++ni) {
      int colg = col0 + wn * 32 + ni * 16 + lm;
      if (colg >= gN) continue;
#pragma unroll
      for (int r = 0; r < 4; ++r) {
        int rowg = row0 + wm * 64 + mi * 16 + lr + r;
        C[(size_t)rowg * gN + colg] = acc[mi][ni][r];
      }
    }
}

// grid-stride decoder agg (vector, Hc=256, tanh, h/m out) — per-element math identical
__device__ __forceinline__ void dec_agg4_grid(int gid0, int gsize,
    const float* __restrict__ AB, const float* __restrict__ bias,
    const int* __restrict__ idx,
    short* __restrict__ outh, short* __restrict__ outm) {
  const int rows = 14976, per = 4992, n = 39, Hc = 256, s2s = 512;
  int total = rows * 64;
  for (int u = gid0; u < total; u += gsize) {
    int r = u >> 6, hq = u & 63;
    int h = hq << 2;
    int d = r / per, rloc = r - d * per;
    int b = rloc / n;
    float4 av = *(const float4*)&AB[(size_t)r * s2s + h];
    float4 bv = *(const float4*)&bias[h];
    float a0 = av.x + bv.x, a1 = av.y + bv.y, a2 = av.z + bv.z, a3 = av.w + bv.w;
    const int* ir = idx + ((size_t)d * per + rloc) * KNN_;
    int base = d * per + b * n;
    int nb[KNN_];
#pragma unroll
    for (int k = 0; k < KNN_; ++k) nb[k] = base + ir[k];
    float m0 = -INFINITY, m1 = -INFINITY, m2 = -INFINITY, m3 = -INFINITY;
#pragma unroll
    for (int k = 0; k < KNN_; ++k) {
      float4 bb = *(const float4*)&AB[(size_t)nb[k] * s2s + Hc + h];
      m0 = fmaxf(m0, fmaxf(a0 + bb.x, 0.f));
      m1 = fmaxf(m1, fmaxf(a1 + bb.y, 0.f));
      m2 = fmaxf(m2, fmaxf(a2 + bb.z, 0.f));
      m3 = fmaxf(m3, fmaxf(a3 + bb.w, 0.f));
    }
    m0 = tanhf(m0); m1 = tanhf(m1); m2 = tanhf(m2); m3 = tanhf(m3);
    size_t o = (size_t)r * Hc + h;
    short h0, mm0, l0, h1, mm1, l1, h2, mm2, l2, h3, mm3, l3;
    f2b3(m0, h0, mm0, l0); f2b3(m1, h1, mm1, l1);
    f2b3(m2, h2, mm2, l2); f2b3(m3, h3, mm3, l3);
    short4v vh = {h0, h1, h2, h3};
    short4v vm = {mm0, mm1, mm2, mm3};
    *(short4v*)&outh[o] = vh;
    *(short4v*)&outm[o] = vm;
  }
}

// grid-stride decoder final agg (scalar, Hc=39, linear, f32 out)
__device__ __forceinline__ void dec_aggs_grid(int gid0, int gsize,
    const float* __restrict__ AB, const float* __restrict__ bias,
    const int* __restrict__ idx, float* __restrict__ out) {
  const int rows = 14976, per = 4992, n = 39, Hc = 39, s2 = 78;
  int total = rows * Hc;
  for (int t = gid0; t < total; t += gsize) {
    int r = t / Hc, h = t - r * Hc;
    int d = r / per, rloc = r - d * per;
    int b = rloc / n;
    float av = AB[(size_t)r * s2 + h] + bias[h];
    const int* ir = idx + ((size_t)d * per + rloc) * KNN_;
    int base = d * per + b * n;
    float m = -INFINITY;
    for (int k = 0; k < KNN_; ++k) {
      float v = av + AB[(size_t)(base + ir[k]) * s2 + Hc + h];
      v = fmaxf(v, 0.f);
      m = fmaxf(m, v);
    }
    out[t] = m;
  }
}

// ======== cooperative decoder: 3 stages in one kernel, 5 grid syncs, 512 blocks ========
// Role loops reproduce the exact 852-role block mapping of the 6-dispatch path -> bit-exact.
// 512 blocks need only 2 blocks/CU (LDS 32KB, 8 waves, VGPR<=128) — co-residency safe.
struct DecP {
  const short *xoh, *xom, *wt3h, *wt3m, *wt2h, *wt2m, *wt6h, *wt6m;
  const float *b3, *b2, *b6;
  short *t1h, *t1m, *t2h, *t2m;
  float *AB3, *outdec;
  int *idxb;
  size_t S, ABS, C3S;
};

__global__ __launch_bounds__(512) void dec_coop_kernel(DecP p) {
  extern __shared__ char smem[];
  cg::grid_group grid = cg::this_grid();
  int bid = blockIdx.x;
  int nbk = (int)gridDim.x;
  int gid0 = bid * 512 + threadIdx.x;
  int gsize = nbk * 512;
  // stage 1 kg: xoutb -> AB3 (W=wcat3); knn idx on xoutb
  for (int role = bid; role < 852; role += nbk) {
    if (role < 384) dec_knn_block(smem, role, p.xoh, p.xom, p.idxb);
    else dec_gemm_block(smem, role - 384, 468, p.xoh, p.xom, p.wt3h, p.wt3m, p.AB3, 512, p.S, p.ABS);
  }
  grid.sync();
  dec_agg4_grid(gid0, gsize, p.AB3, p.b3, p.idxb, p.t1h, p.t1m);
  grid.sync();
  // stage 2 kg: t1b -> AB3 (W=wcat2); knn idx on t1b
  for (int role = bid; role < 852; role += nbk) {
    if (role < 384) dec_knn_block(smem, role, p.t1h, p.t1m, p.idxb);
    else dec_gemm_block(smem, role - 384, 468, p.t1h, p.t1m, p.wt2h, p.wt2m, p.AB3, 512, p.S, p.ABS);
  }
  grid.sync();
  dec_agg4_grid(gid0, gsize, p.AB3, p.b2, p.idxb, p.t2h, p.t2m);
  grid.sync();
  // stage 3 kg: t2b -> AB3 (W=wcat6, gN=78); knn idx on t2b
  for (int role = bid; role < 501; role += nbk) {
    if (role < 384) dec_knn_block(smem, role, p.t2h, p.t2m, p.idxb);
    else dec_gemm_block(smem, role - 384, 117, p.t2h, p.t2m, p.wt6h, p.wt6m, p.AB3, 78, p.S, p.C3S);
  }
  grid.sync();
  dec_aggs_grid(gid0, gsize, p.AB3, p.b6, p.idxb, p.outdec);
}

// ------------- fused degree head: xdeg = relu(relu(relu(X@W4+b4)@W5+b5)·w6+b6) -------------
__global__ __launch_bounds__(256) void degree_head_kernel(
    const short* __restrict__ Xh, const short* __restrict__ Xm,
    const short* __restrict__ W4h, const short* __restrict__ W4m, const float* __restrict__ b4,
    const short* __restrict__ W5h, const short* __restrict__ W5m, const float* __restrict__ b5,
    const float* __restrict__ w6, const float* __restrict__ b6,
    float* __restrict__ xdeg) {
  __shared__ __attribute__((aligned(16))) short Ash[32 * 40];
  __shared__ __attribute__((aligned(16))) short Asm[32 * 40];
  __shared__ __attribute__((aligned(16))) short Bsh[256 * 40];
  __shared__ __attribute__((aligned(16))) short Bsm[256 * 40];
  __shared__ __attribute__((aligned(16))) short H1h[32][264];
  __shared__ __attribute__((aligned(16))) short H1m[32][264];
  __shared__ float rowsum[32];
  int tid = threadIdx.x;
  int wave = tid >> 6, lane = tid & 63;
  int lm = lane & 15, g = lane >> 4, lk = g * 8;
  int row0 = blockIdx.x * 32;

  floatx4 acc[2][4] = {};
  for (int k0 = 0; k0 < 256; k0 += 32) {
    {
      int e = tid;
      int a = e >> 7, rem = e & 127;
      int r = rem >> 2, kc = (rem & 3) * 8;
      const short* src = a ? Xm : Xh;
      short* dst = a ? Asm : Ash;
      *(short8*)&dst[r * 40 + kc] = *(const short8*)&src[(size_t)(row0 + r) * 256 + k0 + kc];
    }
#pragma unroll
    for (int i = 0; i < 8; ++i) {
      int e = tid + i * 256;
      int a = e >> 10, rem = e & 1023;
      int r = rem >> 2, kc = (rem & 3) * 8;
      const short* src = a ? W4m : W4h;
      short* dst = a ? Bsm : Bsh;
      *(short8*)&dst[r * 40 + kc] = *(const short8*)&src[(size_t)r * 256 + k0 + kc];
    }
    __syncthreads();
    short8 afh[2], afm[2];
#pragma unroll
    for (int rt = 0; rt < 2; ++rt) {
      int ro = (rt * 16 + lm) * 40 + lk;
      afh[rt] = *(const short8*)&Ash[ro];
      afm[rt] = *(const short8*)&Asm[ro];
    }
#pragma unroll
    for (int ct = 0; ct < 4; ++ct) {
      int ro = (wave * 64 + ct * 16 + lm) * 40 + lk;
      short8 bfh = *(const short8*)&Bsh[ro];
      short8 bfm = *(const short8*)&Bsm[ro];
#pragma unroll
      for (int rt = 0; rt < 2; ++rt) {
        floatx4 a = acc[rt][ct];
        a = __builtin_amdgcn_mfma_f32_16x16x32_bf16(afh[rt], bfh, a, 0, 0, 0);
        a = __builtin_amdgcn_mfma_f32_16x16x32_bf16(afh[rt], bfm, a, 0, 0, 0);
        a = __builtin_amdgcn_mfma_f32_16x16x32_bf16(afm[rt], bfh, a, 0, 0, 0);
        acc[rt][ct] = a;
      }
    }
    __syncthreads();
  }
#pragma unroll
  for (int rt = 0; rt < 2; ++rt)
#pragma unroll
    for (int ct = 0; ct < 4; ++ct) {
      int col = wave * 64 + ct * 16 + lm;
      float bv = b4[col];
#pragma unroll
      for (int r = 0; r < 4; ++r) {
        int row = rt * 16 + g * 4 + r;
        float v = fmaxf(acc[rt][ct][r] + bv, 0.f);
        short hh = f2b(v);
        H1h[row][col] = hh;
        H1m[row][col] = f2b(v - b2f(hh));
      }
    }
  if (tid < 32) rowsum[tid] = 0.f;
  __syncthreads();

  floatx4 acc2[2][2] = {};
  for (int k0 = 0; k0 < 256; k0 += 32) {
#pragma unroll
    for (int i = 0; i < 4; ++i) {
      int e = tid + i * 256;
      int a = e >> 9, rem = e & 511;
      int r = rem >> 2, kc = (rem & 3) * 8;
      const short* src = a ? W5m : W5h;
      short* dst = a ? Bsm : Bsh;
      *(short8*)&dst[r * 40 + kc] = *(const short8*)&src[(size_t)r * 256 + k0 + kc];
    }
    __syncthreads();
    short8 afh[2], afm[2];
#pragma unroll
    for (int rt = 0; rt < 2; ++rt) {
      afh[rt] = *(const short8*)&H1h[rt * 16 + lm][k0 + lk];
      afm[rt] = *(const short8*)&H1m[rt * 16 + lm][k0 + lk];
    }
#pragma unroll
    for (int ct = 0; ct < 2; ++ct) {
      int ro = (wave * 32 + ct * 16 + lm) * 40 + lk;
      short8 bfh = *(const short8*)&Bsh[ro];
      short8 bfm = *(const short8*)&Bsm[ro];
#pragma unroll
      for (int rt = 0; rt < 2; ++rt) {
        floatx4 a = acc2[rt][ct];
        a = __builtin_amdgcn_mfma_f32_16x16x32_bf16(afh[rt], bfh, a, 0, 0, 0);
        a = __builtin_amdgcn_mfma_f32_16x16x32_bf16(afh[rt], bfm, a, 0, 0, 0);
        a = __builtin_amdgcn_mfma_f32_16x16x32_bf16(afm[rt], bfh, a, 0, 0, 0);
        acc2[rt][ct] = a;
      }
    }
    __syncthreads();
  }
#pragma unroll
  for (int rt = 0; rt < 2; ++rt) {
#pragma unroll
    for (int r = 0; r < 4; ++r) {
      float p = 0.f;
#pragma unroll
      for (int ct = 0; ct < 2; ++ct) {
        int col = wave * 32 + ct * 16 + lm;
        float v = fmaxf(acc2[rt][ct][r] + b5[col], 0.f);
        p += v * w6[col];
      }
#pragma unroll
      for (int off = 1; off < 16; off <<= 1) p += __shfl_xor(p, off, 64);
      if (lm == 0) atomicAdd(&rowsum[rt * 16 + g * 4 + r], p);
    }
  }
  __syncthreads();
  if (tid < 32) xdeg[row0 + tid] = fmaxf(rowsum[tid] + b6[0], 0.f);
}

// scalar edge agg (decoder fallback stage 3); AB is (rows x 2Hc)
__global__ void edge_agg_kernel(const float* __restrict__ AB, const float* __restrict__ bias,
                                const int* __restrict__ idx, int n, int Hc, int act,
                                int rows, int per,
                                float* __restrict__ out,
                                short* __restrict__ outh, short* __restrict__ outm,
                                short* __restrict__ outl) {
  int t = blockIdx.x * blockDim.x + threadIdx.x;
  if (t >= rows * Hc) return;
  int r = t / Hc, h = t - r * Hc;
  int d = r / per, rloc = r - d * per;
  int b = rloc / n;
  int s2 = 2 * Hc;
  float av = AB[(size_t)r * s2 + h] + bias[h];
  const int* ir = idx + ((size_t)d * per + rloc) * KNN_;
  int base = d * per + b * n;
  float m = -INFINITY;
  for (int k = 0; k < KNN_; ++k) {
    float v = av + AB[(size_t)(base + ir[k]) * s2 + Hc + h];
    v = fmaxf(v, 0.f);
    m = fmaxf(m, v);
  }
  if (act == 2) m = tanhf(m);
  if (out) out[t] = m;
  if (outh) {
    short hh, mm, ll;
    f2b3(m, hh, mm, ll);
    outh[t] = hh; outm[t] = mm;
    if (outl) outl[t] = ll;
  }
}

// vectorized edge agg (levels + decoder fallback): 4 features/thread, 8 rows/block.
__global__ __launch_bounds__(256) void edge_agg4_kernel(
    const float* __restrict__ AB, const float* __restrict__ bias,
    const int* __restrict__ idx, int n, int Hc, int act,
    int rows, int per,
    float* __restrict__ out,
    short* __restrict__ outh, short* __restrict__ outm, short* __restrict__ outl,
    double* __restrict__ colsums) {
  __shared__ double lds_s[4][256];
  __shared__ double lds_s2[4][256];
  int tid = threadIdx.x;
  int hq = tid & 63, rl = tid >> 6;
  int h = hq << 2;
  int s2s = 2 * Hc;
  double cs[4] = {0.0, 0.0, 0.0, 0.0}, cs2[4] = {0.0, 0.0, 0.0, 0.0};
#pragma unroll
  for (int sub = 0; sub < 2; ++sub) {
    int r = blockIdx.x * 8 + rl + sub * 4;
    if (r < rows) {
      int d = r / per, rloc = r - d * per;
      int b = rloc / n;
      float4 av = *(const float4*)&AB[(size_t)r * s2s + h];
      float4 bv = *(const float4*)&bias[h];
      float a0 = av.x + bv.x, a1 = av.y + bv.y, a2 = av.z + bv.z, a3 = av.w + bv.w;
      const int* ir = idx + ((size_t)d * per + rloc) * KNN_;
      int base = d * per + b * n;
      int nb[KNN_];
#pragma unroll
      for (int k = 0; k < KNN_; ++k) nb[k] = base + ir[k];
      float m0 = -INFINITY, m1 = -INFINITY, m2 = -INFINITY, m3 = -INFINITY;
#pragma unroll
      for (int k = 0; k < KNN_; ++k) {
        float4 bb = *(const float4*)&AB[(size_t)nb[k] * s2s + Hc + h];
        m0 = fmaxf(m0, fmaxf(a0 + bb.x, 0.f));
        m1 = fmaxf(m1, fmaxf(a1 + bb.y, 0.f));
        m2 = fmaxf(m2, fmaxf(a2 + bb.z, 0.f));
        m3 = fmaxf(m3, fmaxf(a3 + bb.w, 0.f));
      }
      if (act == 2) { m0 = tanhf(m0); m1 = tanhf(m1); m2 = tanhf(m2); m3 = tanhf(m3); }
      size_t o = (size_t)r * Hc + h;
      if (out) *(float4*)&out[o] = make_float4(m0, m1, m2, m3);
      if (outh) {
        short h0, mm0, l0, h1, mm1, l1, h2, mm2, l2, h3, mm3, l3;
        f2b3(m0, h0, mm0, l0); f2b3(m1, h1, mm1, l1);
        f2b3(m2, h2, mm2, l2); f2b3(m3, h3, mm3, l3);
        short4v vh = {h0, h1, h2, h3};
        short4v vm = {mm0, mm1, mm2, mm3};
        *(short4v*)&outh[o] = vh;
        *(short4v*)&outm[o] = vm;
        if (outl) {
          short4v vl = {l0, l1, l2, l3};
          *(short4v*)&outl[o] = vl;
        }
      }
      if (colsums) {
        double d0 = (double)m0, d1 = (double)m1, d2 = (double)m2, d3 = (double)m3;
        cs[0] += d0; cs2[0] += d0 * d0;
        cs[1] += d1; cs2[1] += d1 * d1;
        cs[2] += d2; cs2[2] += d2 * d2;
        cs[3] += d3; cs2[3] += d3 * d3;
      }
    }
  }
  if (colsums) {
#pragma unroll
    for (int j = 0; j < 4; ++j) {
      lds_s[rl][h + j] = cs[j];
      lds_s2[rl][h + j] = cs2[j];
    }
    __syncthreads();
    int c = tid;
    double ss = ((lds_s[0][c] + lds_s[1][c]) + lds_s[2][c]) + lds_s[3][c];
    double ss2 = ((lds_s2[0][c] + lds_s2[1][c]) + lds_s2[2][c]) + lds_s2[3][c];
    atomicAdd(&colsums[c], ss);
    atomicAdd(&colsums[256 + c], ss2);
  }
}

// -------- fused sag select + pool + readout (+gtpred pass-through, +classifier) ----
__global__ __launch_bounds__(1024) void sag_pool_kernel(
    const float* __restrict__ t1,
    const double* __restrict__ colsums, const float* __restrict__ bng,
    const float* __restrict__ bnb, int M,
    const float* __restrict__ pw,
    const float* __restrict__ adj_in, int n, int k,
    const float* __restrict__ pb,
    int* __restrict__ perm, float* __restrict__ adjp,
    const float* __restrict__ deg, const float* __restrict__ xdeg,
    float* __restrict__ gt, float* __restrict__ pred,
    const int* __restrict__ gperm, int gk, float* __restrict__ ggt, float* __restrict__ gpred,
    const int* __restrict__ remap, int accum,
    short* __restrict__ xph, short* __restrict__ xpm, short* __restrict__ xpl,
    short* __restrict__ soh, short* __restrict__ som, float* __restrict__ z,
    const float* __restrict__ W1, const float* __restrict__ b1,
    const float* __restrict__ W2, const float* __restrict__ b2,
    const float* __restrict__ W3, const float* __restrict__ b3,
    float* __restrict__ probs) {
  __shared__ float ys[40], dinv[40], scs[40], tant[40];
  __shared__ int locs[40];
  __shared__ __attribute__((aligned(16))) float t1L[39 * 256];
  __shared__ __attribute__((aligned(16))) float adjL[39 * 39];
  __shared__ __attribute__((aligned(16))) float scshL[512];
  __shared__ __attribute__((aligned(16))) float pmx[4][256];
  __shared__ __attribute__((aligned(16))) float psm[4][256];
  __shared__ __attribute__((aligned(16))) float ca[512];
  __shared__ __attribute__((aligned(16))) float z1s[256];
  __shared__ __attribute__((aligned(16))) float z2s[128];
  __shared__ float lg[2];
  int b = blockIdx.x;
  int i = threadIdx.x;
  int wave = i >> 6, lane = i & 63;
  {
    const float* src = t1 + (size_t)(b * n) * H_;
    int tot = n * H_;
    for (int e = i; e < tot; e += 1024) t1L[e] = src[e];
    const float* asrc = adj_in + (size_t)b * n * n;
    int atot = n * n;
    for (int e = i; e < atot; e += 1024) adjL[e] = asrc[e];
  }
  if (i < 256) {   // bn finalize (exact bn_stats formula)
    double mean = colsums[i] / M;
    double var = colsums[256 + i] / M - mean * mean;
    float rstd = 1.f / sqrtf((float)var + 1e-5f);
    float sc = rstd * bng[i];
    scshL[i] = sc;
    scshL[256 + i] = bnb[i] - (float)mean * sc;
  }
  __syncthreads();
  for (int row = wave; row < n; row += 16) {
    const float* xr = &t1L[row * H_];
    float s = 0.f;
    for (int kk = lane; kk < H_; kk += 64) {
      float v = fmaxf(xr[kk] * scshL[kk] + scshL[H_ + kk], 0.f);
      s += v * pw[kk];
    }
    for (int off = 32; off; off >>= 1) s += __shfl_down(s, off, 64);
    if (lane == 0) ys[row] = s;
  }
  __syncthreads();
  if (i < n) {
    const float* ar = &adjL[i * n];
    float sum = 1.f;
    for (int j = 0; j < n; ++j) sum += ar[j];
    dinv[i] = 1.f / sqrtf(sum);
  }
  __syncthreads();
  if (i < n) {
    const float* ar = &adjL[i * n];
    float acc = 0.f;
    for (int j = 0; j < n; ++j) {
      float a = ar[j] + (i == j ? 1.f : 0.f);
      acc += a * dinv[j] * ys[j];
    }
    scs[i] = dinv[i] * acc + pb[0];
  }
  __syncthreads();
  if (i < n) {   // rank-based stable descending top-k (ties -> lowest index)
    float si = scs[i];
    int rank = 0;
    for (int j = 0; j < n; ++j) {
      float sj = scs[j];
      rank += (sj > si || (sj == si && j < i)) ? 1 : 0;
    }
    if (rank < k) {
      tant[rank] = tanhf(si);
      locs[rank] = i;
      perm[b * k + rank] = b * n + i;
    }
  }
  __syncthreads();
  if (adjp) {
    for (int e = threadIdx.x; e < k * k; e += 1024) {
      int t1i = e / k, t2i = e - t1i * k;
      adjp[(size_t)b * k * k + e] = adjL[locs[t1i] * n + locs[t2i]];
    }
  }
  if (gt && threadIdx.x < k) {
    int p = b * n + locs[threadIdx.x];
    gt[b * k + threadIdx.x] = deg[p];
    pred[b * k + threadIdx.x] = xdeg[p];
  }
  if (ggt && threadIdx.x < gk) {
    int p = gperm[b * gk + threadIdx.x];
    ggt[b * gk + threadIdx.x] = deg[p];
    gpred[b * gk + threadIdx.x] = xdeg[p];
  }
  int hc = i & 255;
  int rg = i >> 8;
  float sc = scshL[hc], sh = scshL[H_ + hc];
  float mx = -INFINITY, sm = 0.f;
  for (int r = rg; r < k; r += 4) {
    int loc = locs[r];
    float tg = tant[r];
    float v = fmaxf(t1L[loc * H_ + hc] * sc + sh, 0.f) * tg;
    short hh, mm, ll;
    f2b3(v, hh, mm, ll);
    size_t xo = ((size_t)(b * k + r)) * H_ + hc;
    xph[xo] = hh; xpm[xo] = mm; xpl[xo] = ll;
    int own = b * n + loc;
    int tgt = remap ? remap[own] : own;
    size_t so = (size_t)tgt * H_ + hc;
    soh[so] = hh; som[so] = mm;
    float vq = b2f(hh) + b2f(mm) + b2f(ll);
    mx = fmaxf(mx, vq);
    sm += vq;
  }
  pmx[rg][hc] = mx;
  psm[rg][hc] = sm;
  __syncthreads();
  if (i < 256) {
    float m0 = fmaxf(fmaxf(pmx[0][hc], pmx[1][hc]), fmaxf(pmx[2][hc], pmx[3][hc]));
    float s0 = ((psm[0][hc] + psm[1][hc]) + psm[2][hc]) + psm[3][hc];
    float* zb = z + (size_t)b * 2 * H_;
    float mean = s0 / (float)k;
    float zr1, zr2;
    if (accum) { zr1 = zb[hc] + m0; zr2 = zb[H_ + hc] + mean; zb[hc] = zr1; zb[H_ + hc] = zr2; }
    else       { zr1 = m0;  zr2 = mean; zb[hc] = zr1; zb[H_ + hc] = zr2; }
    if (probs) { ca[hc] = zr1; ca[H_ + hc] = zr2; }
  }
  if (probs) {
    __syncthreads();
    if (i < 256) {
      int c = hc;
      float s = 0.f;
      for (int kk = 0; kk < 512; kk += 4) {
        float4 av = *(const float4*)&ca[kk];
        s += av.x * W1[(size_t)kk * 256 + c];
        s += av.y * W1[(size_t)(kk + 1) * 256 + c];
        s += av.z * W1[(size_t)(kk + 2) * 256 + c];
        s += av.w * W1[(size_t)(kk + 3) * 256 + c];
      }
      z1s[c] = fmaxf(s + b1[c], 0.f);
    }
    __syncthreads();
    if (i < 128) {
      int c = i;
      float s = 0.f;
      for (int kk = 0; kk < 256; kk += 4) {
        float4 av = *(const float4*)&z1s[kk];
        s += av.x * W2[(size_t)kk * 128 + c];
        s += av.y * W2[(size_t)(kk + 1) * 128 + c];
        s += av.z * W2[(size_t)(kk + 2) * 128 + c];
        s += av.w * W2[(size_t)(kk + 3) * 128 + c];
      }
      z2s[c] = fmaxf(s + b2[c], 0.f);
    }
    __syncthreads();
    if (wave < 2) {
      float s = 0.f;
      for (int kk = lane; kk < 128; kk += 64) s += z2s[kk] * W3[(size_t)kk * 2 + wave];
      for (int off = 32; off; off >>= 1) s += __shfl_down(s, off, 64);
      if (lane == 0) lg[wave] = s + b3[wave];
    }
    __syncthreads();
    if (i == 0) {
      float aa = lg[0], cc = lg[1];
      float m = fmaxf(aa, cc);
      float ea = expf(aa - m), ec = expf(cc - m);
      float inv = 1.f / (ea + ec);
      probs[2 * b] = ea * inv;
      probs[2 * b + 1] = ec * inv;
    }
  }
}

extern "C" void kernel_launch(void* const* d_in, const int* in_sizes, int n_in,
                              void* d_out, int out_size, void* d_ws, size_t ws_size,
                              hipStream_t stream) {
  auto in = [&](int i) { return (const float*)d_in[i]; };
  const float* x      = in(0);
  const float* adj    = in(1);
  const float* w_mlp1 = in(2);  const float* b_mlp1 = in(3);
  const float* w_mlp2 = in(4);  const float* b_mlp2 = in(5);
  const float* w_mlp3 = in(6);  const float* b_mlp3 = in(7);
  const float* w_mlp6 = in(8);  const float* b_mlp6 = in(9);
  const float* bn1_g = in(10);  const float* bn1_b = in(11);
  const float* bn2_g = in(12);  const float* bn2_b = in(13);
  const float* bn3_g = in(14);  const float* bn3_b = in(15);
  const float* p1_w = in(16);   const float* p1_b = in(17);
  const float* p2_w = in(18);   const float* p2_b = in(19);
  const float* p3_w = in(20);   const float* p3_b = in(21);
  const float* lin1_w = in(22); const float* lin1_b = in(23);
  const float* lin2_w = in(24); const float* lin2_b = in(25);
  const float* lin3_w = in(26); const float* lin3_b = in(27);
  const float* lin4_w = in(28); const float* lin4_b = in(29);
  const float* lin5_w = in(30); const float* lin5_b = in(31);
  const float* lin6_w = in(32); const float* lin6_b = in(33);

  float* out = (float*)d_out;
  float* out_probs = out;
  float* out_dec1  = out_probs + 256;            // 3 x 4992*39 contiguous
  float* out_gt1   = out_dec1 + 3 * 4992 * 39;
  float* out_pred1 = out_gt1 + 4096;
  float* out_gt2   = out_pred1 + 4096;
  float* out_pred2 = out_gt2 + 3328;
  float* out_gt3   = out_pred2 + 3328;
  float* out_pred3 = out_gt3 + 2688;

  char* base = (char*)d_ws;
  size_t off = 0;
  auto allocf = [&](size_t n) -> float* {
    float* p = (float*)(base + off);
    off += ((n * sizeof(float) + 255) & ~(size_t)255);
    return p;
  };
  auto alloci = [&](size_t n) -> int* {
    int* p = (int*)(base + off);
    off += ((n * sizeof(int) + 255) & ~(size_t)255);
    return p;
  };
  auto allocs = [&](size_t n) -> short* {
    short* p = (short*)(base + off);
    off += ((n * sizeof(short) + 255) & ~(size_t)255);
    return p;
  };
  auto allocd = [&](size_t n) -> double* {
    double* p = (double*)(base + off);
    off += ((n * sizeof(double) + 255) & ~(size_t)255);
    return p;
  };

  const size_t S = (size_t)4992 * 256;
  const size_t AB_S = (size_t)4992 * 512;
  const int SI = 4992 * KNN_;

  short* wt1h = allocs(512 * 64); short* wt1m = allocs(512 * 64); short* wt1l = allocs(512 * 64);
  short* wt2h = allocs(512 * 256); short* wt2m = allocs(512 * 256); short* wt2l = allocs(512 * 256);
  short* wt3h = allocs(512 * 256); short* wt3m = allocs(512 * 256); short* wt3l = allocs(512 * 256);
  short* wt6h = allocs(78 * 256);  short* wt6m = allocs(78 * 256);
  short* l4h = allocs(256 * 256);  short* l4m = allocs(256 * 256);
  short* l5h = allocs(128 * 256);  short* l5m = allocs(128 * 256);
  short* xsph = allocs(4992 * 64); short* xspm = allocs(4992 * 64); short* xspl = allocs(4992 * 64);
  float* deg  = allocf(4992);
  float* xdeg = allocf(4992);
  int* idxb = alloci(3 * SI);
  float* AB3 = allocf(3 * AB_S);
  float* trunk_t1 = allocf(S);
  double* bnsum = allocd(3 * 512);
  short* xph = allocs((size_t)4096 * 256); short* xpm = allocs((size_t)4096 * 256); short* xpl = allocs((size_t)4096 * 256);
  short* xoutb_h = allocs(3 * S);
  short* xoutb_m = allocs(3 * S);
  short* t1b_h = allocs(3 * S);
  short* t1b_m = allocs(3 * S);
  float* adj1 = allocf(128 * 32 * 32);
  float* adj2 = allocf(128 * 26 * 26);
  int* perm1 = alloci(4096); int* perm2 = alloci(3328); int* perm3 = alloci(2688);
  float* z  = allocf(128 * 512);
  if (off > ws_size) return;

  // t2b aliases xoutb (dead after decoder stage 1)
  short* t2b_h = xoutb_h; short* t2b_m = xoutb_m;

  const size_t LDS3 = 6 * 128 * 32 * sizeof(short);          // 49152: 3-term gemm (>= knn 21.2KB)
  const size_t LDS2 = 4 * 128 * 32 * sizeof(short);          // 32768: 2-term gemm/coop

  // ---- prep (incl. xoutb zeroing task 8 + bnsum zeroing task 9) ----
  prep_kernel<<<6627, 256, 0, stream>>>(
      w_mlp1, w_mlp2, w_mlp3, w_mlp6, lin4_w, lin5_w, x, adj,
      wt1h, wt1m, wt1l, wt2h, wt2m, wt2l, wt3h, wt3m, wt3l, wt6h, wt6m,
      l4h, l4m, l5h, l5m, xsph, xspm, xspl, deg, xoutb_h, bnsum);

  // ---- level 1 ----
  knn_gemm_kernel<<<B_ + 4 * 39, 512, LDS3, stream>>>(
      xsph, xspm, xspl, 3, 64, N_, 64, idxb, B_,
      xsph, xspm, xspl, 3, 64, wt1h, wt1m, wt1l, AB3, 4992, 512, 39, 0, 0);
  edge_agg4_kernel<<<4992 / 8, 256, 0, stream>>>(AB3, b_mlp1, idxb, N_, 256, 0, 4992, 4992,
                                                 trunk_t1, nullptr, nullptr, nullptr, bnsum);
  sag_pool_kernel<<<B_, 1024, 0, stream>>>(
      trunk_t1, bnsum, bn1_g, bn1_b, 4992, p1_w, adj, N_, K1_, p1_b,
      perm1, adj1, nullptr, nullptr, nullptr, nullptr,
      nullptr, 0, nullptr, nullptr,
      nullptr, 0, xph, xpm, xpl, xoutb_h, xoutb_m, z,
      nullptr, nullptr, nullptr, nullptr, nullptr, nullptr, nullptr);
  degree_head_kernel<<<156, 256, 0, stream>>>(
      xoutb_h, xoutb_m, l4h, l4m, lin4_b, l5h, l5m, lin5_b, lin6_w, lin6_b, xdeg);

  // ---- level 2 (also emits level-1 gt/pred) ----
  knn_gemm_kernel<<<B_ + 4 * 32, 512, LDS3, stream>>>(
      xph, xpm, xpl, 3, 256, K1_, 256, idxb, B_,
      xph, xpm, xpl, 3, 256, wt2h, wt2m, wt2l, AB3, 4096, 512, 32, 0, 0);
  edge_agg4_kernel<<<4096 / 8, 256, 0, stream>>>(AB3, b_mlp2, idxb, K1_, 256, 0, 4096, 4096,
                                                 trunk_t1, nullptr, nullptr, nullptr, bnsum + 512);
  sag_pool_kernel<<<B_, 1024, 0, stream>>>(
      trunk_t1, bnsum + 512, bn2_g, bn2_b, 4096, p2_w, adj1, K1_, K2_, p2_b,
      perm2, adj2, deg, xdeg, out_gt2, out_pred2,
      perm1, K1_, out_gt1, out_pred1,
      perm1, 1, xph, xpm, xpl, xoutb_h + S, xoutb_m + S, z,
      nullptr, nullptr, nullptr, nullptr, nullptr, nullptr, nullptr);

  // ---- level 3 (+ fused classifier) ----
  knn_gemm_kernel<<<B_ + 4 * 26, 512, LDS3, stream>>>(
      xph, xpm, xpl, 3, 256, K2_, 256, idxb, B_,
      xph, xpm, xpl, 3, 256, wt3h, wt3m, wt3l, AB3, 3328, 512, 26, 0, 0);
  edge_agg4_kernel<<<3328 / 8, 256, 0, stream>>>(AB3, b_mlp3, idxb, K2_, 256, 0, 3328, 3328,
                                                 trunk_t1, nullptr, nullptr, nullptr, bnsum + 1024);
  sag_pool_kernel<<<B_, 1024, 0, stream>>>(
      trunk_t1, bnsum + 1024, bn3_g, bn3_b, 3328, p3_w, adj2, K2_, K3_, p3_b,
      perm3, nullptr, deg, xdeg, out_gt3, out_pred3,
      nullptr, 0, nullptr, nullptr,
      perm2, 1, xph, xpm, xpl, xoutb_h + 2 * S, xoutb_m + 2 * S, z,
      lin1_w, lin1_b, lin2_w, lin2_b, lin3_w, lin3_b, out_probs);

  // ---- decoders: cooperative (1 dispatch, 5 grid syncs) when co-residency verified;
  //      else identical-numerics 6-dispatch fallback ----
  DecP p;
  p.xoh = xoutb_h; p.xom = xoutb_m;
  p.wt3h = wt3h; p.wt3m = wt3m;
  p.wt2h = wt2h; p.wt2m = wt2m;
  p.wt6h = wt6h; p.wt6m = wt6m;
  p.b3 = b_mlp3; p.b2 = b_mlp2; p.b6 = b_mlp6;
  p.t1h = t1b_h; p.t1m = t1b_m;
  p.t2h = t2b_h; p.t2m = t2b_m;
  p.AB3 = AB3; p.outdec = out_dec1;
  p.idxb = idxb;
  p.S = S; p.ABS = AB_S; p.C3S = (size_t)4992 * 78;

  int maxB = 0;
  bool coop =
      (hipOccupancyMaxActiveBlocksPerMultiprocessor(&maxB, dec_coop_kernel, 512, LDS2)
           == hipSuccess) && maxB >= 2;       // 512 blocks over 256 CUs
  if (coop) {
    void* kargs[] = { (void*)&p };
    coop = hipLaunchCooperativeKernel(reinterpret_cast<const void*>(dec_coop_kernel),
                                      dim3(512), dim3(512), kargs, (unsigned)LDS2,
                                      stream) == hipSuccess;
  }
  if (!coop) {
    knn_gemm_kernel<<<3 * B_ + 4 * 39 * 3, 512, LDS2, stream>>>(
        xoutb_h, xoutb_m, nullptr, 2, 256, N_, 256, idxb, 3 * B_,
        xoutb_h, xoutb_m, nullptr, 2, 256, wt3h, wt3m, nullptr, AB3, 4992, 512, 39, S, AB_S);
    edge_agg4_kernel<<<3 * 4992 / 8, 256, 0, stream>>>(
        AB3, b_mlp3, idxb, N_, 256, 2, 3 * 4992, 4992, nullptr, t1b_h, t1b_m, nullptr, nullptr);
    knn_gemm_kernel<<<3 * B_ + 4 * 39 * 3, 512, LDS2, stream>>>(
        t1b_h, t1b_m, nullptr, 2, 256, N_, 256, idxb, 3 * B_,
        t1b_h, t1b_m, nullptr, 2, 256, wt2h, wt2m, nullptr, AB3, 4992, 512, 39, S, AB_S);
    edge_agg4_kernel<<<3 * 4992 / 8, 256, 0, stream>>>(
        AB3, b_mlp2, idxb, N_, 256, 2, 3 * 4992, 4992, nullptr, t2b_h, t2b_m, nullptr, nullptr);
    knn_gemm_kernel<<<3 * B_ + 1 * 39 * 3, 512, LDS2, stream>>>(
        t2b_h, t2b_m, nullptr, 2, 256, N_, 256, idxb, 3 * B_,
        t2b_h, t2b_m, nullptr, 2, 256, wt6h, wt6m, nullptr, AB3, 4992, 78, 39, S, (size_t)4992 * 78);
    edge_agg_kernel<<<cdiv(3 * 4992 * 39, 256), 256, 0, stream>>>(
        AB3, b_mlp6, idxb, N_, 39, 0, 3 * 4992, 4992, out_dec1, nullptr, nullptr, nullptr);
  }
}